// Round 6
// baseline (911.749 us; speedup 1.0000x reference)
//
#include <hip/hip_runtime.h>

// SemiseparableLayer on MI355X (gfx950) — v7: v6 (verified, 605us) + occupancy/latency fixes.
// v6 lesson: k3 is work-proportional-stall bound; occupancy fell to 3 blocks/CU (LDS 50176)
// giving a 1.33-round schedule. v7:
//  * k3/k1 LDS -> 39,936 B -> 4 blocks/CU; k3 grid 1024 = EXACTLY one round.
//    - C/D/G fragments: per-lane 16B register loads from the L2-hot blobs (prefetched one
//      stage ahead) instead of LDS staging. Same bytes -> bit-identical numerics.
//    - B/F blob planes compacted to stride 20 (bank-spread ok); blob = 7680B, staged as
//      7x1KB global_load_lds + 2x width-4 tail calls (all lanes active, no exec games).
//  * RMW second-touch operands prefetched one iteration ahead (same-thread ordering).
//  * k1: single shared T plane (v6-k3-verified sequential pattern).
// Everything else (arithmetic, layouts, out protocol, k2, k_prep structure, modes) = v6.

#define BATCH 4096
#define NCH   16
#define CHS   32
#define SROWS (BATCH + 32)
#define TSTR  36

typedef __attribute__((ext_vector_type(8))) short short8;
typedef __attribute__((ext_vector_type(4))) float f32x4;
typedef short8 __attribute__((may_alias)) short8a;
typedef f32x4 __attribute__((may_alias)) f32x4a;
typedef unsigned __attribute__((may_alias)) uinta;

#define MFMA16(a, b, c) __builtin_amdgcn_mfma_f32_16x16x32_bf16(a, b, c, 0, 0, 0)

__device__ __forceinline__ unsigned short bf16u(float x) {
  unsigned u = __builtin_bit_cast(unsigned, x);
  u += 0x7fffu + ((u >> 16) & 1u);
  return (unsigned short)(u >> 16);
}
__device__ __forceinline__ float bf2f(unsigned short u) {
  return __builtin_bit_cast(float, ((unsigned)u) << 16);
}
__device__ __forceinline__ unsigned pk2(float a, float b) {
  return (unsigned)bf16u(a) | (((unsigned)bf16u(b)) << 16);
}
template <int DT>
__device__ __forceinline__ const void* eptr(const void* b, long e) {
  return (const char*)b + e * (DT ? 4 : 2);
}

// ---------------- async global->LDS ----------------
__device__ __forceinline__ void gload16(const void* g, void* lds) {
  __builtin_amdgcn_global_load_lds((const __attribute__((address_space(1))) void*)g,
                                   (__attribute__((address_space(3))) void*)lds, 16, 0, 0);
}
__device__ __forceinline__ void gload4(const void* g, void* lds) {
  __builtin_amdgcn_global_load_lds((const __attribute__((address_space(1))) void*)g,
                                   (__attribute__((address_space(3))) void*)lds, 4, 0, 0);
}
// 7680-byte blob: waves 0-2 stage 2x1KB; wave 3 stages 1KB + 2x256B (width-4, 64 lanes)
__device__ __forceinline__ void stage_blob75(const short* g, short* lds, int w, int lane) {
  if (w < 3) {
#pragma unroll
    for (int c = 0; c < 2; ++c) {
      const int ob = (w * 2 + c) * 1024;
      gload16((const char*)g + ob + lane * 16, (char*)lds + ob);
    }
  } else {
    gload16((const char*)g + 6144 + lane * 16, (char*)lds + 6144);
    gload4((const char*)g + 7168 + lane * 4, (char*)lds + 7168);
    gload4((const char*)g + 7424 + lane * 4, (char*)lds + 7424);
  }
}

// ---------------- converting stagers (mode 0; verified) ----------------
template <int DT, int ROWS, int COLS, int PSTR>
__device__ __forceinline__ void stage2(const void* gp, short* hi, short* lo, int tid) {
  if constexpr (DT == 0) {
    const uinta* gu = (const uinta*)gp;
    for (int i = tid; i < ROWS * COLS / 2; i += 256) {
      int r = i / (COLS / 2), c = i - r * (COLS / 2);
      ((uinta*)(hi + r * PSTR))[c] = gu[i];
    }
  } else {
    const float* gf = (const float*)gp;
    for (int i = tid; i < ROWS * COLS; i += 256) {
      int r = i / COLS, c = i - r * COLS;
      float v = gf[i];
      unsigned short h = bf16u(v);
      hi[r * PSTR + c] = (short)h;
      lo[r * PSTR + c] = (short)bf16u(v - bf2f(h));
    }
  }
}
template <int DT, int ROWS, int COLS, int PSTR>
__device__ __forceinline__ void stage1(const void* gp, short* hi, int tid) {
  if constexpr (DT == 0) {
    const uinta* gu = (const uinta*)gp;
    for (int i = tid; i < ROWS * COLS / 2; i += 256) {
      int r = i / (COLS / 2), c = i - r * (COLS / 2);
      ((uinta*)(hi + r * PSTR))[c] = gu[i];
    }
  } else {
    const float* gf = (const float*)gp;
    for (int i = tid; i < ROWS * COLS; i += 256) {
      int r = i / COLS, c = i - r * COLS;
      hi[r * PSTR + c] = (short)bf16u(gf[i]);
    }
  }
}

// ---------------- fragment loaders ----------------
__device__ __forceinline__ short8 ldfrag32(const short* l, int lane, int nbase) {
  int n = nbase + (lane & 15), q = lane >> 4;
  return *(const short8a*)(l + n * 40 + q * 8);
}
template <int PSTR>
__device__ __forceinline__ short8 ldfrag16(const short* l, int lane, int nbase) {
  int n = nbase + (lane & 15), q = lane >> 4;
  short8 z = {};
  if (q < 2) z = *(const short8a*)(l + n * PSTR + q * 8);
  return z;
}

__device__ __forceinline__ void twr(const f32x4* acc, float* T, int lane) {
  const int c = lane & 15, q = lane >> 4;
#pragma unroll
  for (int h = 0; h < 2; ++h)
#pragma unroll
    for (int r = 0; r < 4; ++r) T[(q * 4 + r) * TSTR + h * 16 + c] = acc[h][r];
}
__device__ __forceinline__ void trd(const float* T, int lane, short8& hi, short8& lo) {
  const int m = lane & 15, q = lane >> 4;
  const float* p = T + m * TSTR + q * 8;
#pragma unroll
  for (int j = 0; j < 8; ++j) {
    float v = p[j];
    unsigned short h = bf16u(v);
    hi[j] = (short)h;
    lo[j] = (short)bf16u(v - bf2f(h));
  }
}

// ---------------- u loaders (v6 verbatim) ----------------
template <int DT> struct URaw;
template <> struct URaw<0> { short8 s; };
template <> struct URaw<1> { f32x4 a, b; };

template <int DT>
__device__ __forceinline__ URaw<DT> ldu_raw(const void* U, size_t off) {
  URaw<DT> r;
  if constexpr (DT == 0) {
    r.s = *(const short8a*)((const short*)U + off);
  } else {
    const f32x4a* p = (const f32x4a*)((const float*)U + off);
    r.a = p[0];
    r.b = p[1];
  }
  return r;
}
template <int DT>
__device__ __forceinline__ void u_cvt(const URaw<DT>& r, short8& uhi, short8& ulo) {
  if constexpr (DT == 0) {
    uhi = r.s;
    ulo = short8{};
  } else {
#pragma unroll
    for (int j = 0; j < 4; ++j) {
      float v = r.a[j];
      unsigned short h = bf16u(v);
      uhi[j] = (short)h;
      ulo[j] = (short)bf16u(v - bf2f(h));
    }
#pragma unroll
    for (int j = 0; j < 4; ++j) {
      float v = r.b[j];
      unsigned short h = bf16u(v);
      uhi[4 + j] = (short)h;
      ulo[4 + j] = (short)bf16u(v - bf2f(h));
    }
  }
}
template <int DT, int MODE> struct UL {
  URaw<DT> r;
  __device__ __forceinline__ void fetch(const void* U, const short*, size_t row, int k, int qq) {
    r = ldu_raw<DT>(U, row * 8192 + (size_t)k * 16 + qq * 8);
  }
  __device__ __forceinline__ void get(short8& hi, short8& lo) const { u_cvt<DT>(r, hi, lo); }
};
template <> struct UL<1, 2> {
  short8 h, l;
  __device__ __forceinline__ void fetch(const void*, const short* Ub, size_t row, int k, int qq) {
    const short* p = Ub + (row * 1024 + (size_t)k * 2 + qq) * 16;
    h = *(const short8a*)p;
    l = *(const short8a*)(p + 8);
  }
  __device__ __forceinline__ void get(short8& hi, short8& lo) const { hi = h; lo = l; }
};

template <int DT>
__device__ __forceinline__ float ldbias(const void* b, int i) {
  if constexpr (DT == 0) return bf2f((unsigned short)((const short*)b)[i]);
  else return ((const float*)b)[i];
}

// one state update; BSTR = B-plane stride (20 blob layout / 24 legacy)
template <int DT, int BSTR>
__device__ __forceinline__ void step_state(const short8& Xhi, const short8& Xlo,
                                           const short8& uhi, const short8& ulo,
                                           const short* Mhi, const short* Mlo,
                                           const short* Bhi, const short* Blo,
                                           f32x4* out, int lane) {
#pragma unroll
  for (int h = 0; h < 2; ++h) {
    const f32x4 z4 = {0.f, 0.f, 0.f, 0.f};
    short8 bA = ldfrag32(Mhi, lane, h * 16);
    f32x4 ax = MFMA16(Xhi, bA, z4);
    ax = MFMA16(Xlo, bA, ax);
    short8 bB = ldfrag16<BSTR>(Bhi, lane, h * 16);
    ax = MFMA16(uhi, bB, ax);
    if constexpr (DT) {
      short8 bAl = ldfrag32(Mlo, lane, h * 16);
      ax = MFMA16(Xhi, bAl, ax);
      ax = MFMA16(ulo, bB, ax);
      short8 bBl = ldfrag16<BSTR>(Blo, lane, h * 16);
      ax = MFMA16(uhi, bBl, ax);
    }
    out[h] = ax;
  }
}

// ---------------- dtype detector ----------------
__global__ void k_detect(const unsigned short* __restrict__ U16, int* __restrict__ flag) {
  int lane = threadIdx.x;
  int bad = 0;
  for (int i = lane; i < 512; i += 64) {
    int e = (U16[i] >> 7) & 0xFF;
    bad += ((e > 134) || (e < 96 && e != 0)) ? 1 : 0;
  }
#pragma unroll
  for (int s = 32; s; s >>= 1) bad += __shfl_xor(bad, s);
  if (lane == 0) *flag = (bad > 48) ? 1 : 0;
}

// ---------------- k_prep: blob layout Ahi[32][40]|Alo|Bhi[32][20]|Blo (7680B used of 8KB)
template <int DT, int ROWS, int COLS, int PSTR, bool LO>
__device__ __forceinline__ void cvt_mat(const void* gp, short* hi, short* lo, int tid) {
  if constexpr (DT == 0) {
    const unsigned short* gs = (const unsigned short*)gp;
    for (int i = tid; i < ROWS * COLS; i += 256) {
      int r = i / COLS, c = i - r * COLS;
      hi[r * PSTR + c] = (short)gs[i];
    }
  } else {
    const float* gf = (const float*)gp;
    for (int i = tid; i < ROWS * COLS; i += 256) {
      int r = i / COLS, c = i - r * COLS;
      float v = gf[i];
      unsigned short h = bf16u(v);
      hi[r * PSTR + c] = (short)h;
      if constexpr (LO) lo[r * PSTR + c] = (short)bf16u(v - bf2f(h));
    }
  }
}
template <int DT>
__global__ __launch_bounds__(256) void k_prep(
    const int* __restrict__ flagp,
    const void* __restrict__ Am, const void* __restrict__ Bm, const void* __restrict__ Cm,
    const void* __restrict__ Dm, const void* __restrict__ Em, const void* __restrict__ Fm,
    const void* __restrict__ Gm,
    short* __restrict__ ABb, short* __restrict__ EFb, short* __restrict__ CDb,
    short* __restrict__ Gb) {
  if (*flagp != DT) return;
  const int k = blockIdx.x, tid = threadIdx.x;
  short* ab = ABb + (size_t)k * 4096;
  short* ef = EFb + (size_t)k * 4096;
  short* cd = CDb + (size_t)k * 1024;
  short* gb = Gb + (size_t)k * 1024;
  cvt_mat<DT, 32, 32, 40, true>(eptr<DT>(Am, (long)k * 1024), ab, ab + 1280, tid);
  cvt_mat<DT, 32, 16, 20, true>(eptr<DT>(Bm, (long)k * 512), ab + 2560, ab + 3200, tid);
  cvt_mat<DT, 32, 32, 40, true>(eptr<DT>(Em, (long)k * 1024), ef, ef + 1280, tid);
  cvt_mat<DT, 32, 16, 20, true>(eptr<DT>(Fm, (long)k * 512), ef + 2560, ef + 3200, tid);
  cvt_mat<DT, 16, 32, 40, false>(eptr<DT>(Cm, (long)k * 512), cd, nullptr, tid);
  cvt_mat<DT, 16, 16, 24, false>(eptr<DT>(Dm, (long)k * 256), cd + 640, nullptr, tid);
  cvt_mat<DT, 16, 32, 40, false>(eptr<DT>(Gm, (long)k * 512), gb, nullptr, tid);
}
__global__ __launch_bounds__(256) void k_prepU(const int* __restrict__ flagp,
                                               const float* __restrict__ Uf,
                                               short* __restrict__ Ub) {
  if (*flagp != 1) return;
  const size_t i = (size_t)blockIdx.x * 256 + threadIdx.x;
  const f32x4a* p = (const f32x4a*)(Uf + i * 8);
  f32x4 a = p[0], b = p[1];
  short8 hi, lo;
#pragma unroll
  for (int j = 0; j < 4; ++j) {
    unsigned short h = bf16u(a[j]);
    hi[j] = (short)h;
    lo[j] = (short)bf16u(a[j] - bf2f(h));
  }
#pragma unroll
  for (int j = 0; j < 4; ++j) {
    unsigned short h = bf16u(b[j]);
    hi[4 + j] = (short)h;
    lo[4 + j] = (short)bf16u(b[j] - bf2f(h));
  }
  *(short8a*)(Ub + i * 16) = hi;
  *(short8a*)(Ub + i * 16 + 8) = lo;
}

// ---------------- K1: chunk-local scans (single shared T plane; 4 blocks/CU) ----------
template <int DT, int MODE>
__global__ __launch_bounds__(256, 4) void k1_scan(
    const int* __restrict__ flagp, const void* __restrict__ U,
    const void* __restrict__ Am, const void* __restrict__ Bm,
    const void* __restrict__ Em, const void* __restrict__ Fm,
    const short* __restrict__ ABb, const short* __restrict__ EFb,
    const short* __restrict__ Ub,
    float* __restrict__ Sc, float* __restrict__ Sa) {
  if (*flagp != DT) return;
  constexpr int ABSZ = (MODE >= 1) ? 3840 : 4096;
  constexpr int BLO = (MODE >= 1) ? 3200 : 3328;
  constexpr int BSTR = (MODE >= 1) ? 20 : 24;
  const int ch = blockIdx.x, tile = blockIdx.y;
  const bool ident = (tile == 64);
  const int tid = threadIdx.x, lane = tid & 63, w = tid >> 6;
  const int s = ch * CHS;
  __shared__ __align__(16) short bAB[2][ABSZ];
  __shared__ __align__(16) short bEF[2][ABSZ];
  __shared__ __align__(16) float T[4][16 * TSTR];

  short8 Xhi = {}, Xlo = {}, Zhi = {}, Zlo = {};
  if (ident) {
    const int m = lane & 15, q = lane >> 4;
    short8 id = {};
#pragma unroll
    for (int j = 0; j < 8; ++j) id[j] = ((q * 8 + j) == (w * 16 + m)) ? (short)0x3F80 : (short)0;
    Xhi = id; Zhi = id;
  }

  auto stAB = [&](int k, int b) {
    if constexpr (MODE >= 1) {
      stage_blob75(ABb + (size_t)k * 4096, bAB[b], w, lane);
    } else {
      stage2<DT, 32, 32, 40>(eptr<DT>(Am, (long)k * 1024), bAB[b], bAB[b] + 1280, tid);
      stage2<DT, 32, 16, 24>(eptr<DT>(Bm, (long)k * 512), bAB[b] + 2560, bAB[b] + 3328, tid);
    }
  };
  auto stEF = [&](int k, int b) {
    if constexpr (MODE >= 1) {
      stage_blob75(EFb + (size_t)k * 4096, bEF[b], w, lane);
    } else {
      stage2<DT, 32, 32, 40>(eptr<DT>(Em, (long)k * 1024), bEF[b], bEF[b] + 1280, tid);
      stage2<DT, 32, 16, 24>(eptr<DT>(Fm, (long)k * 512), bEF[b] + 2560, bEF[b] + 3328, tid);
    }
  };

  stAB(s, 0);
  stEF(s + CHS - 1, 0);

  const size_t row = (size_t)(ident ? 0 : (tile * 64 + w * 16 + (lane & 15)));
  const int qq = (lane >> 4) & 1;
  UL<DT, MODE> upc, upa;
  if (!ident) {
    upc.fetch(U, Ub, row, s, qq);
    upa.fetch(U, Ub, row, s + CHS - 1, qq);
  }
  __syncthreads();

  f32x4 aX[2], aZ[2];
#pragma unroll 2
  for (int t = 0; t < CHS; ++t) {
    const int kc = s + t, ka = s + CHS - 1 - t, buf = t & 1;
    if (t < CHS - 1) {
      stAB(kc + 1, buf ^ 1);
      stEF(ka - 1, buf ^ 1);
    }
    short8 uch = {}, ucl = {}, uah = {}, ual = {};
    if (!ident) {
      upc.get(uch, ucl);
      upa.get(uah, ual);
      if (t < CHS - 1) {
        upc.fetch(U, Ub, row, kc + 1, qq);
        upa.fetch(U, Ub, row, ka - 1, qq);
      }
    }
    step_state<DT, BSTR>(Xhi, Xlo, uch, ucl, bAB[buf], bAB[buf] + 1280, bAB[buf] + 2560,
                         bAB[buf] + BLO, aX, lane);
    step_state<DT, BSTR>(Zhi, Zlo, uah, ual, bEF[buf], bEF[buf] + 1280, bEF[buf] + 2560,
                         bEF[buf] + BLO, aZ, lane);
    twr(aX, T[w], lane);
    trd(T[w], lane, Xhi, Xlo);
    twr(aZ, T[w], lane);   // WAR on shared plane: same-wave in-order DS (v6-verified)
    trd(T[w], lane, Zhi, Zlo);
    __syncthreads();
  }

  if (!ident || w < 2) {
    const int grow = tile * 64 + w * 16;
#pragma unroll
    for (int h = 0; h < 2; ++h)
#pragma unroll
      for (int r = 0; r < 4; ++r) {
        const int m = (lane >> 4) * 4 + r, col = h * 16 + (lane & 15);
        const size_t off = ((size_t)ch * SROWS + grow + m) * 32 + col;
        Sc[off] = aX[h][r];
        Sa[off] = aZ[h][r];
      }
  }
}

// ---------------- K2 (v1 verbatim) ----------------
__global__ __launch_bounds__(256) void k2_comb(float* __restrict__ Sc, float* __restrict__ Sa) {
  const int dir = blockIdx.y;
  const int r = threadIdx.x >> 5, j = threadIdx.x & 31;
  const int row = blockIdx.x * 8 + r;
  float* S = dir ? Sa : Sc;
  __shared__ float P[32][33];
  __shared__ float xs[8][33];
  float x = 0.f;
  for (int it = 0; it < NCH; ++it) {
    const int ch = dir ? (NCH - 1 - it) : it;
    const size_t base = ((size_t)ch * SROWS + row) * 32 + j;
    const float s_local = S[base];
    for (int i = threadIdx.x; i < 1024; i += 256)
      P[i >> 5][i & 31] = S[((size_t)ch * SROWS + BATCH + (i >> 5)) * 32 + (i & 31)];
    xs[r][j] = x;
    __syncthreads();
    S[base] = x;
    float acc = s_local;
#pragma unroll
    for (int m = 0; m < 32; ++m) acc += xs[r][m] * P[m][j];
    x = acc;
    __syncthreads();
  }
}

// ---------------- K3 merged dual-chain (mode >= 1): 4 blocks/CU, reg-frags, RMW prefetch
template <int DT, int MODE>
__global__ __launch_bounds__(256, 4) void k3_merged(
    const int* __restrict__ flagp, const void* __restrict__ U, const void* __restrict__ biasv,
    const short* __restrict__ ABb, const short* __restrict__ EFb,
    const short* __restrict__ CDb, const short* __restrict__ Gb,
    const short* __restrict__ Ub,
    const float* __restrict__ xin, const float* __restrict__ zin,
    void* __restrict__ out) {
  if (*flagp != DT) return;
  const int ch = blockIdx.x, tile = blockIdx.y;
  const int tid = threadIdx.x, lane = tid & 63, w = tid >> 6;
  const int s = ch * CHS;
  __shared__ __align__(16) short bAB[2][3840];
  __shared__ __align__(16) short bEF[2][3840];
  __shared__ __align__(16) float T[4][16 * TSTR];

  const int cidx = lane & 15, quad = lane >> 4, qq = quad & 1;
  const size_t row = (size_t)(tile * 64 + w * 16 + cidx);

  short8 Xhi, Xlo, Zhi, Zlo;
  {
    const float* xp = xin + ((size_t)ch * SROWS + row) * 32 + quad * 8;
    const float* zp = zin + ((size_t)ch * SROWS + row) * 32 + quad * 8;
#pragma unroll
    for (int j = 0; j < 8; ++j) {
      float v = xp[j];
      unsigned short h = bf16u(v);
      Xhi[j] = (short)h;
      Xlo[j] = (short)bf16u(v - bf2f(h));
      float z = zp[j];
      unsigned short hz = bf16u(z);
      Zhi[j] = (short)hz;
      Zlo[j] = (short)bf16u(z - bf2f(hz));
    }
  }

  stage_blob75(ABb + (size_t)s * 4096, bAB[0], w, lane);
  stage_blob75(EFb + (size_t)(s + CHS - 1) * 4096, bEF[0], w, lane);
  UL<DT, MODE> upc, upa;
  upc.fetch(U, Ub, row, s, qq);
  upa.fetch(U, Ub, row, s + CHS - 1, qq);
  // C/D/G fragment register prefetch (16B per lane from L2-hot blobs)
  short8 cfr, dfr = {}, gfr;
  {
    const short* cdk = CDb + (size_t)s * 1024;
    cfr = *(const short8a*)(cdk + cidx * 40 + quad * 8);
    if (quad < 2) dfr = *(const short8a*)(cdk + 640 + cidx * 24 + quad * 8);
    gfr = *(const short8a*)(Gb + (size_t)(s + CHS - 1) * 1024 + cidx * 40 + quad * 8);
  }
  unsigned rp0 = 0, rp1 = 0, rq0 = 0, rq1 = 0;  // RMW prefetch regs (DT=1 path)
  __syncthreads();

  f32x4 aX[2], aZ[2];
#pragma unroll 2
  for (int t = 0; t < CHS; ++t) {
    const int kc = s + t, ka = s + CHS - 1 - t, buf = t & 1;
    if (t < CHS - 1) {
      stage_blob75(ABb + (size_t)(kc + 1) * 4096, bAB[buf ^ 1], w, lane);
      stage_blob75(EFb + (size_t)(ka - 1) * 4096, bEF[buf ^ 1], w, lane);
    }
    short8 uh, ul, vh, vl;
    upc.get(uh, ul);
    upa.get(vh, vl);
    if (t < CHS - 1) {
      upc.fetch(U, Ub, row, kc + 1, qq);
      upa.fetch(U, Ub, row, ka - 1, qq);
    }
    const f32x4 z4 = {0.f, 0.f, 0.f, 0.f};
    // causal y at kc (register fragments)
    f32x4 yc = MFMA16(Xhi, cfr, z4);
    yc = MFMA16(Xlo, cfr, yc);
    yc = MFMA16(uh, dfr, yc);
    if constexpr (DT) yc = MFMA16(ul, dfr, yc);
    // anti y at ka
    f32x4 yz = MFMA16(Zhi, gfr, z4);
    yz = MFMA16(Zlo, gfr, yz);
    // prefetch next-stage fragments
    if (t < CHS - 1) {
      const short* cdk = CDb + (size_t)(kc + 1) * 1024;
      short8 ncf = *(const short8a*)(cdk + cidx * 40 + quad * 8);
      short8 ndf = {};
      if (quad < 2) ndf = *(const short8a*)(cdk + 640 + cidx * 24 + quad * 8);
      short8 ngf = *(const short8a*)(Gb + (size_t)(ka - 1) * 1024 + cidx * 40 + quad * 8);
      cfr = ncf; dfr = ndf; gfr = ngf;
    }

    const float bv = ldbias<DT>(biasv, kc * 16 + cidx);
    const size_t rbase = (size_t)(tile * 64 + w * 16 + quad * 4) * 8192;
    const size_t oc = rbase + (size_t)kc * 16 + cidx;
    const size_t oa = rbase + (size_t)ka * 16 + cidx;
    if constexpr (DT == 0) {
      short* o = (short*)out;
      if (t < CHS / 2) {
#pragma unroll
        for (int r = 0; r < 4; ++r) o[oc + (size_t)r * 8192] = (short)bf16u(yc[r] + bv);
#pragma unroll
        for (int r = 0; r < 4; ++r) o[oa + (size_t)r * 8192] = (short)bf16u(yz[r]);
      } else {
#pragma unroll
        for (int r = 0; r < 4; ++r) {
          const float c = bf2f((unsigned short)o[oc + (size_t)r * 8192]);
          o[oc + (size_t)r * 8192] = (short)bf16u(c + yc[r] + bv);
        }
#pragma unroll
        for (int r = 0; r < 4; ++r) {
          const float c = bf2f((unsigned short)o[oa + (size_t)r * 8192]);
          o[oa + (size_t)r * 8192] = (short)bf16u(c + yz[r]);
        }
      }
    } else {
      float* o = (float*)out;
      if (t < CHS / 2) {  // first touch: packed bf16-pair partials (verified rounding)
        *(uinta*)(o + oc) = pk2(yc[0] + bv, yc[1] + bv);
        *(uinta*)(o + oc + 2 * 8192) = pk2(yc[2] + bv, yc[3] + bv);
        *(uinta*)(o + oa) = pk2(yz[0], yz[1]);
        *(uinta*)(o + oa + 2 * 8192) = pk2(yz[2], yz[3]);
      } else {  // second touch: finalize with PREFETCHED operands
        o[oc + 0 * 8192] = bf2f((unsigned short)(rp0 & 0xffffu)) + yc[0] + bv;
        o[oc + 1 * 8192] = bf2f((unsigned short)(rp0 >> 16)) + yc[1] + bv;
        o[oc + 2 * 8192] = bf2f((unsigned short)(rp1 & 0xffffu)) + yc[2] + bv;
        o[oc + 3 * 8192] = bf2f((unsigned short)(rp1 >> 16)) + yc[3] + bv;
        o[oa + 0 * 8192] = bf2f((unsigned short)(rq0 & 0xffffu)) + yz[0];
        o[oa + 1 * 8192] = bf2f((unsigned short)(rq0 >> 16)) + yz[1];
        o[oa + 2 * 8192] = bf2f((unsigned short)(rq1 & 0xffffu)) + yz[2];
        o[oa + 3 * 8192] = bf2f((unsigned short)(rq1 >> 16)) + yz[3];
      }
      // prefetch RMW operands for t+1 (written by the other chain at iter 31-(t+1) <= t,
      // same thread; at t=15 it's this iteration's own stores -> forwarded)
      if (t + 1 >= CHS / 2 && t < CHS - 1) {
        const size_t oc1 = rbase + (size_t)(kc + 1) * 16 + cidx;
        const size_t oa1 = rbase + (size_t)(ka - 1) * 16 + cidx;
        rp0 = *(const uinta*)(o + oc1);
        rp1 = *(const uinta*)(o + oc1 + 2 * 8192);
        rq0 = *(const uinta*)(o + oa1);
        rq1 = *(const uinta*)(o + oa1 + 2 * 8192);
      }
    }
    // state updates (blob B-stride 20, Blo at +3200)
    step_state<DT, 20>(Xhi, Xlo, uh, ul, bAB[buf], bAB[buf] + 1280, bAB[buf] + 2560,
                       bAB[buf] + 3200, aX, lane);
    step_state<DT, 20>(Zhi, Zlo, vh, vl, bEF[buf], bEF[buf] + 1280, bEF[buf] + 2560,
                       bEF[buf] + 3200, aZ, lane);
    twr(aX, T[w], lane);
    trd(T[w], lane, Xhi, Xlo);
    twr(aZ, T[w], lane);
    trd(T[w], lane, Zhi, Zlo);
    __syncthreads();
  }
}

// ---------------- K3 legacy two-phase (mode 0 fallback; v5 verbatim) ----------
template <int DT>
__global__ __launch_bounds__(256, 4) void k3_legacy(
    const int* __restrict__ flagp, const void* __restrict__ U,
    const void* __restrict__ Am, const void* __restrict__ Bm,
    const void* __restrict__ Cm, const void* __restrict__ Dm,
    const void* __restrict__ Em, const void* __restrict__ Fm,
    const void* __restrict__ Gm, const void* __restrict__ biasv,
    const float* __restrict__ xin, const float* __restrict__ zin,
    void* __restrict__ out) {
  if (*flagp != DT) return;
  const int ch = blockIdx.x, tile = blockIdx.y;
  const int tid = threadIdx.x, lane = tid & 63, w = tid >> 6;
  const int s = ch * CHS;
  __shared__ __align__(16) short bM[2][4096];
  __shared__ __align__(16) short bO[2][1024];
  __shared__ __align__(16) float T[4][16 * TSTR];
  const int cidx = lane & 15, quad = lane >> 4, qq = quad & 1;
  const size_t row = (size_t)(tile * 64 + w * 16 + cidx);

  auto stC = [&](int k, int b) {
    stage2<DT, 32, 32, 40>(eptr<DT>(Am, (long)k * 1024), bM[b], bM[b] + 1280, tid);
    stage2<DT, 32, 16, 24>(eptr<DT>(Bm, (long)k * 512), bM[b] + 2560, bM[b] + 3328, tid);
    stage1<DT, 16, 32, 40>(eptr<DT>(Cm, (long)k * 512), bO[b], tid);
    stage1<DT, 16, 16, 24>(eptr<DT>(Dm, (long)k * 256), bO[b] + 640, tid);
  };
  auto stA = [&](int k, int b) {
    stage2<DT, 32, 32, 40>(eptr<DT>(Em, (long)k * 1024), bM[b], bM[b] + 1280, tid);
    stage2<DT, 32, 16, 24>(eptr<DT>(Fm, (long)k * 512), bM[b] + 2560, bM[b] + 3328, tid);
    stage1<DT, 16, 32, 40>(eptr<DT>(Gm, (long)k * 512), bO[b], tid);
  };

  short8 Xhi, Xlo;
  {
    const float* xp = xin + ((size_t)ch * SROWS + row) * 32 + quad * 8;
#pragma unroll
    for (int j = 0; j < 8; ++j) {
      float v = xp[j];
      unsigned short h = bf16u(v);
      Xhi[j] = (short)h;
      Xlo[j] = (short)bf16u(v - bf2f(h));
    }
  }
  stC(s, 0);
  UL<DT, 0> up;
  up.fetch(U, nullptr, row, s, qq);
  __syncthreads();

  f32x4 aX[2];
#pragma unroll 2
  for (int t = 0; t < CHS; ++t) {
    const int k = s + t, buf = t & 1;
    if (t < CHS - 1) stC(k + 1, buf ^ 1);
    short8 uh, ul;
    up.get(uh, ul);
    if (t < CHS - 1) up.fetch(U, nullptr, row, k + 1, qq);
    const f32x4 z4 = {0.f, 0.f, 0.f, 0.f};
    const short8 cf = ldfrag32(bO[buf], lane, 0);
    f32x4 ya = MFMA16(Xhi, cf, z4);
    ya = MFMA16(Xlo, cf, ya);
    const short8 df = ldfrag16<24>(bO[buf] + 640, lane, 0);
    ya = MFMA16(uh, df, ya);
    if constexpr (DT) ya = MFMA16(ul, df, ya);
    const float bv = ldbias<DT>(biasv, k * 16 + cidx);
    {
      const size_t obase = (size_t)(tile * 64 + w * 16 + quad * 4) * 8192 + (size_t)k * 16 + cidx;
      if constexpr (DT == 0) {
        short* o = (short*)out;
#pragma unroll
        for (int r = 0; r < 4; ++r) o[obase + (size_t)r * 8192] = (short)bf16u(ya[r] + bv);
      } else {
        float* o = (float*)out;
#pragma unroll
        for (int r = 0; r < 4; ++r) o[obase + (size_t)r * 8192] = ya[r] + bv;
      }
    }
    step_state<DT, 24>(Xhi, Xlo, uh, ul, bM[buf], bM[buf] + 1280, bM[buf] + 2560,
                       bM[buf] + 3328, aX, lane);
    twr(aX, T[w], lane);
    trd(T[w], lane, Xhi, Xlo);
    __syncthreads();
  }

  short8 Zhi, Zlo;
  {
    const float* zp = zin + ((size_t)ch * SROWS + row) * 32 + quad * 8;
#pragma unroll
    for (int j = 0; j < 8; ++j) {
      float v = zp[j];
      unsigned short h = bf16u(v);
      Zhi[j] = (short)h;
      Zlo[j] = (short)bf16u(v - bf2f(h));
    }
  }
  stA(s + CHS - 1, 0);
  up.fetch(U, nullptr, row, s + CHS - 1, qq);
  __syncthreads();

  f32x4 aZ[2];
#pragma unroll 2
  for (int t = 0; t < CHS; ++t) {
    const int k = s + CHS - 1 - t, buf = t & 1;
    if (t < CHS - 1) stA(k - 1, buf ^ 1);
    short8 uh, ul;
    up.get(uh, ul);
    if (t < CHS - 1) up.fetch(U, nullptr, row, k - 1, qq);
    const f32x4 z4 = {0.f, 0.f, 0.f, 0.f};
    const short8 gf = ldfrag32(bO[buf], lane, 0);
    f32x4 ya = MFMA16(Zhi, gf, z4);
    ya = MFMA16(Zlo, gf, ya);
    {
      const size_t obase = (size_t)(tile * 64 + w * 16 + quad * 4) * 8192 + (size_t)k * 16 + cidx;
      if constexpr (DT == 0) {
        short* o = (short*)out;
#pragma unroll
        for (int r = 0; r < 4; ++r) {
          const float c = bf2f((unsigned short)o[obase + (size_t)r * 8192]);
          o[obase + (size_t)r * 8192] = (short)bf16u(c + ya[r]);
        }
      } else {
        float* o = (float*)out;
#pragma unroll
        for (int r = 0; r < 4; ++r) o[obase + (size_t)r * 8192] += ya[r];
      }
    }
    step_state<DT, 24>(Zhi, Zlo, uh, ul, bM[buf], bM[buf] + 1280, bM[buf] + 2560,
                       bM[buf] + 3328, aZ, lane);
    twr(aZ, T[w], lane);
    trd(T[w], lane, Zhi, Zlo);
    __syncthreads();
  }
}

extern "C" void kernel_launch(void* const* d_in, const int* in_sizes, int n_in,
                              void* d_out, int out_size, void* d_ws, size_t ws_size,
                              hipStream_t stream) {
  (void)in_sizes; (void)n_in; (void)out_size;
  const void* U = d_in[0];
  const void* A = d_in[1];
  const void* B = d_in[2];
  const void* C = d_in[3];
  const void* D = d_in[4];
  const void* E = d_in[5];
  const void* F = d_in[6];
  const void* G = d_in[7];
  const void* bias = d_in[8];

  constexpr size_t SC1 = (size_t)NCH * SROWS * 32;
  constexpr size_t BLOBS = (size_t)512 * 8192 * 2 + (size_t)512 * 2048 * 2;
  constexpr size_t UBB = (size_t)BATCH * 1024 * 32;
  constexpr size_t NEED1 = 1024 + BLOBS + SC1 * 8;
  constexpr size_t NEED2 = NEED1 + UBB;
  const int mode = (ws_size >= NEED2) ? 2 : (ws_size >= NEED1 ? 1 : 0);

  char* base = (char*)d_ws;
  int* flag = (int*)base;
  short* ABb = (short*)(base + 1024);
  short* EFb = ABb + (size_t)512 * 4096;
  short* CDb = EFb + (size_t)512 * 4096;
  short* Gb = CDb + (size_t)512 * 1024;
  float* Sc = (mode >= 1) ? (float*)(Gb + (size_t)512 * 1024) : (float*)(base + 1024);
  float* Sa = Sc + SC1;
  short* Ub = (short*)(Sa + SC1);

  k_detect<<<1, 64, 0, stream>>>((const unsigned short*)U, flag);
  if (mode >= 1) {
    k_prep<0><<<512, 256, 0, stream>>>(flag, A, B, C, D, E, F, G, ABb, EFb, CDb, Gb);
    k_prep<1><<<512, 256, 0, stream>>>(flag, A, B, C, D, E, F, G, ABb, EFb, CDb, Gb);
  }
  if (mode == 2) k_prepU<<<16384, 256, 0, stream>>>(flag, (const float*)U, Ub);

  if (mode >= 1) {
    k1_scan<0, 1><<<dim3(NCH, 65), 256, 0, stream>>>(flag, U, A, B, E, F, ABb, EFb, Ub, Sc, Sa);
    if (mode == 2)
      k1_scan<1, 2><<<dim3(NCH, 65), 256, 0, stream>>>(flag, U, A, B, E, F, ABb, EFb, Ub, Sc, Sa);
    else
      k1_scan<1, 1><<<dim3(NCH, 65), 256, 0, stream>>>(flag, U, A, B, E, F, ABb, EFb, Ub, Sc, Sa);
    k2_comb<<<dim3(BATCH / 8, 2), 256, 0, stream>>>(Sc, Sa);
    k3_merged<0, 1><<<dim3(NCH, 64), 256, 0, stream>>>(flag, U, bias, ABb, EFb, CDb, Gb, Ub,
                                                       Sc, Sa, d_out);
    if (mode == 2)
      k3_merged<1, 2><<<dim3(NCH, 64), 256, 0, stream>>>(flag, U, bias, ABb, EFb, CDb, Gb, Ub,
                                                         Sc, Sa, d_out);
    else
      k3_merged<1, 1><<<dim3(NCH, 64), 256, 0, stream>>>(flag, U, bias, ABb, EFb, CDb, Gb, Ub,
                                                         Sc, Sa, d_out);
  } else {
    k1_scan<0, 0><<<dim3(NCH, 65), 256, 0, stream>>>(flag, U, A, B, E, F, ABb, EFb, Ub, Sc, Sa);
    k1_scan<1, 0><<<dim3(NCH, 65), 256, 0, stream>>>(flag, U, A, B, E, F, ABb, EFb, Ub, Sc, Sa);
    k2_comb<<<dim3(BATCH / 8, 2), 256, 0, stream>>>(Sc, Sa);
    k3_legacy<0><<<dim3(NCH, 64), 256, 0, stream>>>(flag, U, A, B, C, D, E, F, G, bias,
                                                    Sc, Sa, d_out);
    k3_legacy<1><<<dim3(NCH, 64), 256, 0, stream>>>(flag, U, A, B, C, D, E, F, G, bias,
                                                    Sc, Sa, d_out);
  }
}

// Round 7
// 630.024 us; speedup vs baseline: 1.4472x; 1.4472x over previous
//
#include <hip/hip_runtime.h>

// SemiseparableLayer on MI355X (gfx950) — v8: v6 (verified, 605us) + dual-tile blocks.
// v7 lesson (regression): per-lane global reads of shared C/D/G fragments caused 3.6x HBM
// traffic (4-wave duplication + scatter + LLC thrash). v8 REVERTS to v6's exact memory
// paths (LDS staging via global_load_lds, v6 blob layout) and instead fixes the schedule:
//  * k3/k1 blocks process TWO adjacent tiles of the same chunk: grid 512 (k3) / 16x33 (k1)
//    -> 2 blocks/CU, EXACTLY one round, no tail; 4 independent chains/thread (2x ILP);
//    stage matrices staged once per block serve both tiles; step_pair loads each LDS
//    fragment once and MFMAs both tiles (same per-tile accumulation order = same numerics).
//  * T-plane reused sequentially 4x per iter (v6-verified same-wave WAR pattern).
// k2, k_prep, k_prepU, out protocol, modes: v6 VERBATIM. Mode 0 = v6 fallback paths.

#define BATCH 4096
#define NCH   16
#define CHS   32
#define SROWS (BATCH + 32)
#define TSTR  36

typedef __attribute__((ext_vector_type(8))) short short8;
typedef __attribute__((ext_vector_type(4))) float f32x4;
typedef short8 __attribute__((may_alias)) short8a;
typedef f32x4 __attribute__((may_alias)) f32x4a;
typedef unsigned __attribute__((may_alias)) uinta;

#define MFMA16(a, b, c) __builtin_amdgcn_mfma_f32_16x16x32_bf16(a, b, c, 0, 0, 0)

__device__ __forceinline__ unsigned short bf16u(float x) {
  unsigned u = __builtin_bit_cast(unsigned, x);
  u += 0x7fffu + ((u >> 16) & 1u);
  return (unsigned short)(u >> 16);
}
__device__ __forceinline__ float bf2f(unsigned short u) {
  return __builtin_bit_cast(float, ((unsigned)u) << 16);
}
__device__ __forceinline__ unsigned pk2(float a, float b) {
  return (unsigned)bf16u(a) | (((unsigned)bf16u(b)) << 16);
}
template <int DT>
__device__ __forceinline__ const void* eptr(const void* b, long e) {
  return (const char*)b + e * (DT ? 4 : 2);
}

// ---------------- async global->LDS blob staging (v6 verbatim) ----------------
__device__ __forceinline__ void gload16(const void* g, void* lds) {
  __builtin_amdgcn_global_load_lds((const __attribute__((address_space(1))) void*)g,
                                   (__attribute__((address_space(3))) void*)lds, 16, 0, 0);
}
__device__ __forceinline__ void stage_blob8(const short* g, short* lds, int w, int lane) {
#pragma unroll
  for (int c = 0; c < 2; ++c) {
    const int ob = (w * 2 + c) * 1024;
    gload16((const char*)g + ob + lane * 16, (char*)lds + ob);
  }
}
__device__ __forceinline__ void stage_blob2k(const short* g, short* lds, int w, int lane) {
  if (w < 2) {
    const int ob = w * 1024;
    gload16((const char*)g + ob + lane * 16, (char*)lds + ob);
  }
}

// ---------------- converting stagers (mode 0 fallback; verified) ----------------
template <int DT, int ROWS, int COLS, int PSTR>
__device__ __forceinline__ void stage2(const void* gp, short* hi, short* lo, int tid) {
  if constexpr (DT == 0) {
    const uinta* gu = (const uinta*)gp;
    for (int i = tid; i < ROWS * COLS / 2; i += 256) {
      int r = i / (COLS / 2), c = i - r * (COLS / 2);
      ((uinta*)(hi + r * PSTR))[c] = gu[i];
    }
  } else {
    const float* gf = (const float*)gp;
    for (int i = tid; i < ROWS * COLS; i += 256) {
      int r = i / COLS, c = i - r * COLS;
      float v = gf[i];
      unsigned short h = bf16u(v);
      hi[r * PSTR + c] = (short)h;
      lo[r * PSTR + c] = (short)bf16u(v - bf2f(h));
    }
  }
}
template <int DT, int ROWS, int COLS, int PSTR>
__device__ __forceinline__ void stage1(const void* gp, short* hi, int tid) {
  if constexpr (DT == 0) {
    const uinta* gu = (const uinta*)gp;
    for (int i = tid; i < ROWS * COLS / 2; i += 256) {
      int r = i / (COLS / 2), c = i - r * (COLS / 2);
      ((uinta*)(hi + r * PSTR))[c] = gu[i];
    }
  } else {
    const float* gf = (const float*)gp;
    for (int i = tid; i < ROWS * COLS; i += 256) {
      int r = i / COLS, c = i - r * COLS;
      hi[r * PSTR + c] = (short)bf16u(gf[i]);
    }
  }
}

// ---------------- fragment loaders (v6 verbatim) ----------------
__device__ __forceinline__ short8 ldfrag32(const short* l, int lane, int nbase) {
  int n = nbase + (lane & 15), q = lane >> 4;
  return *(const short8a*)(l + n * 40 + q * 8);
}
__device__ __forceinline__ short8 ldfrag16(const short* l, int lane, int nbase) {
  int n = nbase + (lane & 15), q = lane >> 4;
  short8 z = {};
  if (q < 2) z = *(const short8a*)(l + n * 24 + q * 8);
  return z;
}

__device__ __forceinline__ void twr(const f32x4* acc, float* T, int lane) {
  const int c = lane & 15, q = lane >> 4;
#pragma unroll
  for (int h = 0; h < 2; ++h)
#pragma unroll
    for (int r = 0; r < 4; ++r) T[(q * 4 + r) * TSTR + h * 16 + c] = acc[h][r];
}
__device__ __forceinline__ void trd(const float* T, int lane, short8& hi, short8& lo) {
  const int m = lane & 15, q = lane >> 4;
  const float* p = T + m * TSTR + q * 8;
#pragma unroll
  for (int j = 0; j < 8; ++j) {
    float v = p[j];
    unsigned short h = bf16u(v);
    hi[j] = (short)h;
    lo[j] = (short)bf16u(v - bf2f(h));
  }
}

// ---------------- u loaders (v6 verbatim) ----------------
template <int DT> struct URaw;
template <> struct URaw<0> { short8 s; };
template <> struct URaw<1> { f32x4 a, b; };

template <int DT>
__device__ __forceinline__ URaw<DT> ldu_raw(const void* U, size_t off) {
  URaw<DT> r;
  if constexpr (DT == 0) {
    r.s = *(const short8a*)((const short*)U + off);
  } else {
    const f32x4a* p = (const f32x4a*)((const float*)U + off);
    r.a = p[0];
    r.b = p[1];
  }
  return r;
}
template <int DT>
__device__ __forceinline__ void u_cvt(const URaw<DT>& r, short8& uhi, short8& ulo) {
  if constexpr (DT == 0) {
    uhi = r.s;
    ulo = short8{};
  } else {
#pragma unroll
    for (int j = 0; j < 4; ++j) {
      float v = r.a[j];
      unsigned short h = bf16u(v);
      uhi[j] = (short)h;
      ulo[j] = (short)bf16u(v - bf2f(h));
    }
#pragma unroll
    for (int j = 0; j < 4; ++j) {
      float v = r.b[j];
      unsigned short h = bf16u(v);
      uhi[4 + j] = (short)h;
      ulo[4 + j] = (short)bf16u(v - bf2f(h));
    }
  }
}
template <int DT, int MODE> struct UL {
  URaw<DT> r;
  __device__ __forceinline__ void fetch(const void* U, const short*, size_t row, int k, int qq) {
    r = ldu_raw<DT>(U, row * 8192 + (size_t)k * 16 + qq * 8);
  }
  __device__ __forceinline__ void get(short8& hi, short8& lo) const { u_cvt<DT>(r, hi, lo); }
};
template <> struct UL<1, 2> {
  short8 h, l;
  __device__ __forceinline__ void fetch(const void*, const short* Ub, size_t row, int k, int qq) {
    const short* p = Ub + (row * 1024 + (size_t)k * 2 + qq) * 16;
    h = *(const short8a*)p;
    l = *(const short8a*)(p + 8);
  }
  __device__ __forceinline__ void get(short8& hi, short8& lo) const { hi = h; lo = l; }
};

template <int DT>
__device__ __forceinline__ float ldbias(const void* b, int i) {
  if constexpr (DT == 0) return bf2f((unsigned short)((const short*)b)[i]);
  else return ((const float*)b)[i];
}

// single-tile state update (mode-0 fallback; v6 verbatim)
template <int DT>
__device__ __forceinline__ void step_state(const short8& Xhi, const short8& Xlo,
                                           const short8& uhi, const short8& ulo,
                                           const short* Mhi, const short* Mlo,
                                           const short* Bhi, const short* Blo,
                                           f32x4* out, int lane) {
#pragma unroll
  for (int h = 0; h < 2; ++h) {
    const f32x4 z4 = {0.f, 0.f, 0.f, 0.f};
    short8 bA = ldfrag32(Mhi, lane, h * 16);
    f32x4 ax = MFMA16(Xhi, bA, z4);
    ax = MFMA16(Xlo, bA, ax);
    short8 bB = ldfrag16(Bhi, lane, h * 16);
    ax = MFMA16(uhi, bB, ax);
    if constexpr (DT) {
      short8 bAl = ldfrag32(Mlo, lane, h * 16);
      ax = MFMA16(Xhi, bAl, ax);
      ax = MFMA16(ulo, bB, ax);
      short8 bBl = ldfrag16(Blo, lane, h * 16);
      ax = MFMA16(uhi, bBl, ax);
    }
    out[h] = ax;
  }
}
// paired state update: one fragment load, two tiles (per-tile MFMA order = v6)
template <int DT>
__device__ __forceinline__ void step_pair(const short8& X0h, const short8& X0l,
                                          const short8& u0h, const short8& u0l,
                                          const short8& X1h, const short8& X1l,
                                          const short8& u1h, const short8& u1l,
                                          const short* Mhi, const short* Mlo,
                                          const short* Bhi, const short* Blo,
                                          f32x4* o0, f32x4* o1, int lane) {
#pragma unroll
  for (int h = 0; h < 2; ++h) {
    const f32x4 z4 = {0.f, 0.f, 0.f, 0.f};
    short8 bA = ldfrag32(Mhi, lane, h * 16);
    f32x4 a0 = MFMA16(X0h, bA, z4);
    f32x4 a1 = MFMA16(X1h, bA, z4);
    a0 = MFMA16(X0l, bA, a0);
    a1 = MFMA16(X1l, bA, a1);
    short8 bB = ldfrag16(Bhi, lane, h * 16);
    a0 = MFMA16(u0h, bB, a0);
    a1 = MFMA16(u1h, bB, a1);
    if constexpr (DT) {
      short8 bAl = ldfrag32(Mlo, lane, h * 16);
      a0 = MFMA16(X0h, bAl, a0);
      a1 = MFMA16(X1h, bAl, a1);
      a0 = MFMA16(u0l, bB, a0);
      a1 = MFMA16(u1l, bB, a1);
      short8 bBl = ldfrag16(Blo, lane, h * 16);
      a0 = MFMA16(u0h, bBl, a0);
      a1 = MFMA16(u1h, bBl, a1);
    }
    o0[h] = a0;
    o1[h] = a1;
  }
}

// ---------------- dtype detector ----------------
__global__ void k_detect(const unsigned short* __restrict__ U16, int* __restrict__ flag) {
  int lane = threadIdx.x;
  int bad = 0;
  for (int i = lane; i < 512; i += 64) {
    int e = (U16[i] >> 7) & 0xFF;
    bad += ((e > 134) || (e < 96 && e != 0)) ? 1 : 0;
  }
#pragma unroll
  for (int s = 32; s; s >>= 1) bad += __shfl_xor(bad, s);
  if (lane == 0) *flag = (bad > 48) ? 1 : 0;
}

// ---------------- k_prep (v6 verbatim layout) ----------------
template <int DT, int ROWS, int COLS, int PSTR, bool LO>
__device__ __forceinline__ void cvt_mat(const void* gp, short* hi, short* lo, int tid) {
  if constexpr (DT == 0) {
    const unsigned short* gs = (const unsigned short*)gp;
    for (int i = tid; i < ROWS * COLS; i += 256) {
      int r = i / COLS, c = i - r * COLS;
      hi[r * PSTR + c] = (short)gs[i];
    }
  } else {
    const float* gf = (const float*)gp;
    for (int i = tid; i < ROWS * COLS; i += 256) {
      int r = i / COLS, c = i - r * COLS;
      float v = gf[i];
      unsigned short h = bf16u(v);
      hi[r * PSTR + c] = (short)h;
      if constexpr (LO) lo[r * PSTR + c] = (short)bf16u(v - bf2f(h));
    }
  }
}
template <int DT>
__global__ __launch_bounds__(256) void k_prep(
    const int* __restrict__ flagp,
    const void* __restrict__ Am, const void* __restrict__ Bm, const void* __restrict__ Cm,
    const void* __restrict__ Dm, const void* __restrict__ Em, const void* __restrict__ Fm,
    const void* __restrict__ Gm,
    short* __restrict__ ABb, short* __restrict__ EFb, short* __restrict__ CDb,
    short* __restrict__ Gb) {
  if (*flagp != DT) return;
  const int k = blockIdx.x, tid = threadIdx.x;
  short* ab = ABb + (size_t)k * 4096;
  short* ef = EFb + (size_t)k * 4096;
  short* cd = CDb + (size_t)k * 1024;
  short* gb = Gb + (size_t)k * 1024;
  cvt_mat<DT, 32, 32, 40, true>(eptr<DT>(Am, (long)k * 1024), ab, ab + 1280, tid);
  cvt_mat<DT, 32, 16, 24, true>(eptr<DT>(Bm, (long)k * 512), ab + 2560, ab + 3328, tid);
  cvt_mat<DT, 32, 32, 40, true>(eptr<DT>(Em, (long)k * 1024), ef, ef + 1280, tid);
  cvt_mat<DT, 32, 16, 24, true>(eptr<DT>(Fm, (long)k * 512), ef + 2560, ef + 3328, tid);
  cvt_mat<DT, 16, 32, 40, false>(eptr<DT>(Cm, (long)k * 512), cd, nullptr, tid);
  cvt_mat<DT, 16, 16, 24, false>(eptr<DT>(Dm, (long)k * 256), cd + 640, nullptr, tid);
  cvt_mat<DT, 16, 32, 40, false>(eptr<DT>(Gm, (long)k * 512), gb, nullptr, tid);
}
__global__ __launch_bounds__(256) void k_prepU(const int* __restrict__ flagp,
                                               const float* __restrict__ Uf,
                                               short* __restrict__ Ub) {
  if (*flagp != 1) return;
  const size_t i = (size_t)blockIdx.x * 256 + threadIdx.x;
  const f32x4a* p = (const f32x4a*)(Uf + i * 8);
  f32x4 a = p[0], b = p[1];
  short8 hi, lo;
#pragma unroll
  for (int j = 0; j < 4; ++j) {
    unsigned short h = bf16u(a[j]);
    hi[j] = (short)h;
    lo[j] = (short)bf16u(a[j] - bf2f(h));
  }
#pragma unroll
  for (int j = 0; j < 4; ++j) {
    unsigned short h = bf16u(b[j]);
    hi[4 + j] = (short)h;
    lo[4 + j] = (short)bf16u(b[j] - bf2f(h));
  }
  *(short8a*)(Ub + i * 16) = hi;
  *(short8a*)(Ub + i * 16 + 8) = lo;
}

// ---------------- K1 dual-tile (mode >= 1): grid (NCH, 33), 2 blocks/CU ----------------
template <int DT, int MODE>
__global__ __launch_bounds__(256, 2) void k1_dual(
    const int* __restrict__ flagp, const void* __restrict__ U,
    const short* __restrict__ ABb, const short* __restrict__ EFb,
    const short* __restrict__ Ub,
    float* __restrict__ Sc, float* __restrict__ Sa) {
  if (*flagp != DT) return;
  const int ch = blockIdx.x, y = blockIdx.y;
  const int tile0 = (y < 32) ? 2 * y : 64, tile1 = (y < 32) ? 2 * y + 1 : 64;
  const bool id0 = (tile0 == 64), id1 = (tile1 == 64);
  const int tid = threadIdx.x, lane = tid & 63, w = tid >> 6;
  const int s = ch * CHS;
  __shared__ __align__(16) short bAB[2][4096];
  __shared__ __align__(16) short bEF[2][4096];
  __shared__ __align__(16) float T[4][16 * TSTR];

  short8 X0h = {}, X0l = {}, Z0h = {}, Z0l = {};
  short8 X1h = {}, X1l = {}, Z1h = {}, Z1l = {};
  if (id0 || id1) {
    const int m = lane & 15, q = lane >> 4;
    short8 id = {};
#pragma unroll
    for (int j = 0; j < 8; ++j) id[j] = ((q * 8 + j) == (w * 16 + m)) ? (short)0x3F80 : (short)0;
    if (id0) { X0h = id; Z0h = id; }
    if (id1) { X1h = id; Z1h = id; }
  }

  stage_blob8(ABb + (size_t)s * 4096, bAB[0], w, lane);
  stage_blob8(EFb + (size_t)(s + CHS - 1) * 4096, bEF[0], w, lane);

  const size_t row0 = (size_t)(id0 ? 0 : (tile0 * 64 + w * 16 + (lane & 15)));
  const size_t row1 = (size_t)(id1 ? 0 : (tile1 * 64 + w * 16 + (lane & 15)));
  const int qq = (lane >> 4) & 1;
  UL<DT, MODE> uc0, ua0, uc1, ua1;
  if (!id0) {
    uc0.fetch(U, Ub, row0, s, qq);
    ua0.fetch(U, Ub, row0, s + CHS - 1, qq);
  }
  if (!id1) {
    uc1.fetch(U, Ub, row1, s, qq);
    ua1.fetch(U, Ub, row1, s + CHS - 1, qq);
  }
  __syncthreads();

  f32x4 aX0[2], aZ0[2], aX1[2], aZ1[2];
#pragma unroll 2
  for (int t = 0; t < CHS; ++t) {
    const int kc = s + t, ka = s + CHS - 1 - t, buf = t & 1;
    if (t < CHS - 1) {
      stage_blob8(ABb + (size_t)(kc + 1) * 4096, bAB[buf ^ 1], w, lane);
      stage_blob8(EFb + (size_t)(ka - 1) * 4096, bEF[buf ^ 1], w, lane);
    }
    short8 c0h = {}, c0l = {}, a0h = {}, a0l = {};
    short8 c1h = {}, c1l = {}, a1h = {}, a1l = {};
    if (!id0) {
      uc0.get(c0h, c0l);
      ua0.get(a0h, a0l);
      if (t < CHS - 1) {
        uc0.fetch(U, Ub, row0, kc + 1, qq);
        ua0.fetch(U, Ub, row0, ka - 1, qq);
      }
    }
    if (!id1) {
      uc1.get(c1h, c1l);
      ua1.get(a1h, a1l);
      if (t < CHS - 1) {
        uc1.fetch(U, Ub, row1, kc + 1, qq);
        ua1.fetch(U, Ub, row1, ka - 1, qq);
      }
    }
    step_pair<DT>(X0h, X0l, c0h, c0l, X1h, X1l, c1h, c1l,
                  bAB[buf], bAB[buf] + 1280, bAB[buf] + 2560, bAB[buf] + 3328, aX0, aX1, lane);
    step_pair<DT>(Z0h, Z0l, a0h, a0l, Z1h, Z1l, a1h, a1l,
                  bEF[buf], bEF[buf] + 1280, bEF[buf] + 2560, bEF[buf] + 3328, aZ0, aZ1, lane);
    twr(aX0, T[w], lane);
    trd(T[w], lane, X0h, X0l);
    twr(aZ0, T[w], lane);
    trd(T[w], lane, Z0h, Z0l);
    twr(aX1, T[w], lane);
    trd(T[w], lane, X1h, X1l);
    twr(aZ1, T[w], lane);
    trd(T[w], lane, Z1h, Z1l);
    __syncthreads();
  }

  const int n = lane & 15, q = lane >> 4;
  if (!id0 || w < 2) {
    const int grow = tile0 * 64 + w * 16;
#pragma unroll
    for (int h = 0; h < 2; ++h)
#pragma unroll
      for (int r = 0; r < 4; ++r) {
        const int m = q * 4 + r, col = h * 16 + n;
        const size_t off = ((size_t)ch * SROWS + grow + m) * 32 + col;
        Sc[off] = aX0[h][r];
        Sa[off] = aZ0[h][r];
      }
  }
  if (!id1 || w < 2) {
    const int grow = tile1 * 64 + w * 16;
#pragma unroll
    for (int h = 0; h < 2; ++h)
#pragma unroll
      for (int r = 0; r < 4; ++r) {
        const int m = q * 4 + r, col = h * 16 + n;
        const size_t off = ((size_t)ch * SROWS + grow + m) * 32 + col;
        Sc[off] = aX1[h][r];
        Sa[off] = aZ1[h][r];
      }
  }
}

// ---------------- K1 single-tile (mode 0 fallback; v6 verbatim MODE=0) ----------------
template <int DT>
__global__ __launch_bounds__(256, 4) void k1_scan0(
    const int* __restrict__ flagp, const void* __restrict__ U,
    const void* __restrict__ Am, const void* __restrict__ Bm,
    const void* __restrict__ Em, const void* __restrict__ Fm,
    float* __restrict__ Sc, float* __restrict__ Sa) {
  if (*flagp != DT) return;
  const int ch = blockIdx.x, tile = blockIdx.y;
  const bool ident = (tile == 64);
  const int tid = threadIdx.x, lane = tid & 63, w = tid >> 6;
  const int s = ch * CHS;
  __shared__ __align__(16) short bAB[2][4096];
  __shared__ __align__(16) short bEF[2][4096];
  __shared__ __align__(16) float T[4][16 * TSTR];

  short8 Xhi = {}, Xlo = {}, Zhi = {}, Zlo = {};
  if (ident) {
    const int m = lane & 15, q = lane >> 4;
    short8 id = {};
#pragma unroll
    for (int j = 0; j < 8; ++j) id[j] = ((q * 8 + j) == (w * 16 + m)) ? (short)0x3F80 : (short)0;
    Xhi = id; Zhi = id;
  }

  auto stAB = [&](int k, int b) {
    stage2<DT, 32, 32, 40>(eptr<DT>(Am, (long)k * 1024), bAB[b], bAB[b] + 1280, tid);
    stage2<DT, 32, 16, 24>(eptr<DT>(Bm, (long)k * 512), bAB[b] + 2560, bAB[b] + 3328, tid);
  };
  auto stEF = [&](int k, int b) {
    stage2<DT, 32, 32, 40>(eptr<DT>(Em, (long)k * 1024), bEF[b], bEF[b] + 1280, tid);
    stage2<DT, 32, 16, 24>(eptr<DT>(Fm, (long)k * 512), bEF[b] + 2560, bEF[b] + 3328, tid);
  };

  stAB(s, 0);
  stEF(s + CHS - 1, 0);

  const size_t row = (size_t)(ident ? 0 : (tile * 64 + w * 16 + (lane & 15)));
  const int qq = (lane >> 4) & 1;
  UL<DT, 0> upc, upa;
  if (!ident) {
    upc.fetch(U, nullptr, row, s, qq);
    upa.fetch(U, nullptr, row, s + CHS - 1, qq);
  }
  __syncthreads();

  f32x4 aX[2], aZ[2];
#pragma unroll 2
  for (int t = 0; t < CHS; ++t) {
    const int kc = s + t, ka = s + CHS - 1 - t, buf = t & 1;
    if (t < CHS - 1) {
      stAB(kc + 1, buf ^ 1);
      stEF(ka - 1, buf ^ 1);
    }
    short8 uch = {}, ucl = {}, uah = {}, ual = {};
    if (!ident) {
      upc.get(uch, ucl);
      upa.get(uah, ual);
      if (t < CHS - 1) {
        upc.fetch(U, nullptr, row, kc + 1, qq);
        upa.fetch(U, nullptr, row, ka - 1, qq);
      }
    }
    step_state<DT>(Xhi, Xlo, uch, ucl, bAB[buf], bAB[buf] + 1280, bAB[buf] + 2560,
                   bAB[buf] + 3328, aX, lane);
    step_state<DT>(Zhi, Zlo, uah, ual, bEF[buf], bEF[buf] + 1280, bEF[buf] + 2560,
                   bEF[buf] + 3328, aZ, lane);
    twr(aX, T[w], lane);
    trd(T[w], lane, Xhi, Xlo);
    twr(aZ, T[w], lane);
    trd(T[w], lane, Zhi, Zlo);
    __syncthreads();
  }

  if (!ident || w < 2) {
    const int grow = tile * 64 + w * 16;
#pragma unroll
    for (int h = 0; h < 2; ++h)
#pragma unroll
      for (int r = 0; r < 4; ++r) {
        const int m = (lane >> 4) * 4 + r, col = h * 16 + (lane & 15);
        const size_t off = ((size_t)ch * SROWS + grow + m) * 32 + col;
        Sc[off] = aX[h][r];
        Sa[off] = aZ[h][r];
      }
  }
}

// ---------------- K2 (v1 verbatim) ----------------
__global__ __launch_bounds__(256) void k2_comb(float* __restrict__ Sc, float* __restrict__ Sa) {
  const int dir = blockIdx.y;
  const int r = threadIdx.x >> 5, j = threadIdx.x & 31;
  const int row = blockIdx.x * 8 + r;
  float* S = dir ? Sa : Sc;
  __shared__ float P[32][33];
  __shared__ float xs[8][33];
  float x = 0.f;
  for (int it = 0; it < NCH; ++it) {
    const int ch = dir ? (NCH - 1 - it) : it;
    const size_t base = ((size_t)ch * SROWS + row) * 32 + j;
    const float s_local = S[base];
    for (int i = threadIdx.x; i < 1024; i += 256)
      P[i >> 5][i & 31] = S[((size_t)ch * SROWS + BATCH + (i >> 5)) * 32 + (i & 31)];
    xs[r][j] = x;
    __syncthreads();
    S[base] = x;
    float acc = s_local;
#pragma unroll
    for (int m = 0; m < 32; ++m) acc += xs[r][m] * P[m][j];
    x = acc;
    __syncthreads();
  }
}

// ---------------- K3 dual-tile merged (mode >= 1): grid (NCH, 32), 2 blocks/CU ----------
template <int DT, int MODE>
__global__ __launch_bounds__(256, 2) void k3_dual(
    const int* __restrict__ flagp, const void* __restrict__ U, const void* __restrict__ biasv,
    const short* __restrict__ ABb, const short* __restrict__ EFb,
    const short* __restrict__ CDb, const short* __restrict__ Gb,
    const short* __restrict__ Ub,
    const float* __restrict__ xin, const float* __restrict__ zin,
    void* __restrict__ out) {
  if (*flagp != DT) return;
  const int ch = blockIdx.x, tile0 = blockIdx.y * 2, tile1 = tile0 + 1;
  const int tid = threadIdx.x, lane = tid & 63, w = tid >> 6;
  const int s = ch * CHS;
  __shared__ __align__(16) short bAB[2][4096];
  __shared__ __align__(16) short bEF[2][4096];
  __shared__ __align__(16) short bCD[2][1024];
  __shared__ __align__(16) short bG[2][1024];
  __shared__ __align__(16) float T[4][16 * TSTR];

  const int cidx = lane & 15, quad = lane >> 4, qq = quad & 1;
  const size_t row0 = (size_t)(tile0 * 64 + w * 16 + cidx);
  const size_t row1 = (size_t)(tile1 * 64 + w * 16 + cidx);

  short8 X0h, X0l, Z0h, Z0l, X1h, X1l, Z1h, Z1l;
  {
    auto ld8 = [&](const float* p, short8& hi, short8& lo) {
#pragma unroll
      for (int j = 0; j < 8; ++j) {
        float v = p[j];
        unsigned short h = bf16u(v);
        hi[j] = (short)h;
        lo[j] = (short)bf16u(v - bf2f(h));
      }
    };
    ld8(xin + ((size_t)ch * SROWS + row0) * 32 + quad * 8, X0h, X0l);
    ld8(zin + ((size_t)ch * SROWS + row0) * 32 + quad * 8, Z0h, Z0l);
    ld8(xin + ((size_t)ch * SROWS + row1) * 32 + quad * 8, X1h, X1l);
    ld8(zin + ((size_t)ch * SROWS + row1) * 32 + quad * 8, Z1h, Z1l);
  }

  stage_blob8(ABb + (size_t)s * 4096, bAB[0], w, lane);
  stage_blob2k(CDb + (size_t)s * 1024, bCD[0], w, lane);
  stage_blob8(EFb + (size_t)(s + CHS - 1) * 4096, bEF[0], w, lane);
  stage_blob2k(Gb + (size_t)(s + CHS - 1) * 1024, bG[0], w, lane);
  UL<DT, MODE> uc0, ua0, uc1, ua1;
  uc0.fetch(U, Ub, row0, s, qq);
  ua0.fetch(U, Ub, row0, s + CHS - 1, qq);
  uc1.fetch(U, Ub, row1, s, qq);
  ua1.fetch(U, Ub, row1, s + CHS - 1, qq);
  __syncthreads();

  f32x4 aX0[2], aZ0[2], aX1[2], aZ1[2];
#pragma unroll 2
  for (int t = 0; t < CHS; ++t) {
    const int kc = s + t, ka = s + CHS - 1 - t, buf = t & 1;
    if (t < CHS - 1) {
      stage_blob8(ABb + (size_t)(kc + 1) * 4096, bAB[buf ^ 1], w, lane);
      stage_blob2k(CDb + (size_t)(kc + 1) * 1024, bCD[buf ^ 1], w, lane);
      stage_blob8(EFb + (size_t)(ka - 1) * 4096, bEF[buf ^ 1], w, lane);
      stage_blob2k(Gb + (size_t)(ka - 1) * 1024, bG[buf ^ 1], w, lane);
    }
    short8 u0h, u0l, v0h, v0l, u1h, u1l, v1h, v1l;
    uc0.get(u0h, u0l);
    ua0.get(v0h, v0l);
    uc1.get(u1h, u1l);
    ua1.get(v1h, v1l);
    if (t < CHS - 1) {
      uc0.fetch(U, Ub, row0, kc + 1, qq);
      ua0.fetch(U, Ub, row0, ka - 1, qq);
      uc1.fetch(U, Ub, row1, kc + 1, qq);
      ua1.fetch(U, Ub, row1, ka - 1, qq);
    }
    const f32x4 z4 = {0.f, 0.f, 0.f, 0.f};
    // y outputs: shared fragment loads, per-tile MFMA order = v6
    const short8 cf = ldfrag32(bCD[buf], lane, 0);
    const short8 df = ldfrag16(bCD[buf] + 640, lane, 0);
    const short8 gf = ldfrag32(bG[buf], lane, 0);
    f32x4 yc0 = MFMA16(X0h, cf, z4);
    yc0 = MFMA16(X0l, cf, yc0);
    yc0 = MFMA16(u0h, df, yc0);
    if constexpr (DT) yc0 = MFMA16(u0l, df, yc0);
    f32x4 yz0 = MFMA16(Z0h, gf, z4);
    yz0 = MFMA16(Z0l, gf, yz0);
    f32x4 yc1 = MFMA16(X1h, cf, z4);
    yc1 = MFMA16(X1l, cf, yc1);
    yc1 = MFMA16(u1h, df, yc1);
    if constexpr (DT) yc1 = MFMA16(u1l, df, yc1);
    f32x4 yz1 = MFMA16(Z1h, gf, z4);
    yz1 = MFMA16(Z1l, gf, yz1);

    const float bv = ldbias<DT>(biasv, kc * 16 + cidx);
    auto emit = [&](int tile, const f32x4& yc, const f32x4& yz) {
      const size_t rbase = (size_t)(tile * 64 + w * 16 + quad * 4) * 8192;
      const size_t oc = rbase + (size_t)kc * 16 + cidx;
      const size_t oa = rbase + (size_t)ka * 16 + cidx;
      if constexpr (DT == 0) {
        short* o = (short*)out;
        if (t < CHS / 2) {
#pragma unroll
          for (int r = 0; r < 4; ++r) o[oc + (size_t)r * 8192] = (short)bf16u(yc[r] + bv);
#pragma unroll
          for (int r = 0; r < 4; ++r) o[oa + (size_t)r * 8192] = (short)bf16u(yz[r]);
        } else {
#pragma unroll
          for (int r = 0; r < 4; ++r) {
            const float c = bf2f((unsigned short)o[oc + (size_t)r * 8192]);
            o[oc + (size_t)r * 8192] = (short)bf16u(c + yc[r] + bv);
          }
#pragma unroll
          for (int r = 0; r < 4; ++r) {
            const float c = bf2f((unsigned short)o[oa + (size_t)r * 8192]);
            o[oa + (size_t)r * 8192] = (short)bf16u(c + yz[r]);
          }
        }
      } else {
        float* o = (float*)out;
        if (t < CHS / 2) {
          *(uinta*)(o + oc) = pk2(yc[0] + bv, yc[1] + bv);
          *(uinta*)(o + oc + 2 * 8192) = pk2(yc[2] + bv, yc[3] + bv);
          *(uinta*)(o + oa) = pk2(yz[0], yz[1]);
          *(uinta*)(o + oa + 2 * 8192) = pk2(yz[2], yz[3]);
        } else {
          const unsigned p0 = *(const uinta*)(o + oc);
          const unsigned p1 = *(const uinta*)(o + oc + 2 * 8192);
          o[oc + 0 * 8192] = bf2f((unsigned short)(p0 & 0xffffu)) + yc[0] + bv;
          o[oc + 1 * 8192] = bf2f((unsigned short)(p0 >> 16)) + yc[1] + bv;
          o[oc + 2 * 8192] = bf2f((unsigned short)(p1 & 0xffffu)) + yc[2] + bv;
          o[oc + 3 * 8192] = bf2f((unsigned short)(p1 >> 16)) + yc[3] + bv;
          const unsigned q0 = *(const uinta*)(o + oa);
          const unsigned q1 = *(const uinta*)(o + oa + 2 * 8192);
          o[oa + 0 * 8192] = bf2f((unsigned short)(q0 & 0xffffu)) + yz[0];
          o[oa + 1 * 8192] = bf2f((unsigned short)(q0 >> 16)) + yz[1];
          o[oa + 2 * 8192] = bf2f((unsigned short)(q1 & 0xffffu)) + yz[2];
          o[oa + 3 * 8192] = bf2f((unsigned short)(q1 >> 16)) + yz[3];
        }
      }
    };
    emit(tile0, yc0, yz0);
    emit(tile1, yc1, yz1);

    step_pair<DT>(X0h, X0l, u0h, u0l, X1h, X1l, u1h, u1l,
                  bAB[buf], bAB[buf] + 1280, bAB[buf] + 2560, bAB[buf] + 3328, aX0, aX1, lane);
    step_pair<DT>(Z0h, Z0l, v0h, v0l, Z1h, Z1l, v1h, v1l,
                  bEF[buf], bEF[buf] + 1280, bEF[buf] + 2560, bEF[buf] + 3328, aZ0, aZ1, lane);
    twr(aX0, T[w], lane);
    trd(T[w], lane, X0h, X0l);
    twr(aZ0, T[w], lane);
    trd(T[w], lane, Z0h, Z0l);
    twr(aX1, T[w], lane);
    trd(T[w], lane, X1h, X1l);
    twr(aZ1, T[w], lane);
    trd(T[w], lane, Z1h, Z1l);
    __syncthreads();
  }
}

// ---------------- K3 legacy two-phase (mode 0 fallback; v6 verbatim) ----------
template <int DT>
__global__ __launch_bounds__(256, 4) void k3_legacy(
    const int* __restrict__ flagp, const void* __restrict__ U,
    const void* __restrict__ Am, const void* __restrict__ Bm,
    const void* __restrict__ Cm, const void* __restrict__ Dm,
    const void* __restrict__ Em, const void* __restrict__ Fm,
    const void* __restrict__ Gm, const void* __restrict__ biasv,
    const float* __restrict__ xin, const float* __restrict__ zin,
    void* __restrict__ out) {
  if (*flagp != DT) return;
  const int ch = blockIdx.x, tile = blockIdx.y;
  const int tid = threadIdx.x, lane = tid & 63, w = tid >> 6;
  const int s = ch * CHS;
  __shared__ __align__(16) short bM[2][4096];
  __shared__ __align__(16) short bO[2][1024];
  __shared__ __align__(16) float T[4][16 * TSTR];
  const int cidx = lane & 15, quad = lane >> 4, qq = quad & 1;
  const size_t row = (size_t)(tile * 64 + w * 16 + cidx);

  auto stC = [&](int k, int b) {
    stage2<DT, 32, 32, 40>(eptr<DT>(Am, (long)k * 1024), bM[b], bM[b] + 1280, tid);
    stage2<DT, 32, 16, 24>(eptr<DT>(Bm, (long)k * 512), bM[b] + 2560, bM[b] + 3328, tid);
    stage1<DT, 16, 32, 40>(eptr<DT>(Cm, (long)k * 512), bO[b], tid);
    stage1<DT, 16, 16, 24>(eptr<DT>(Dm, (long)k * 256), bO[b] + 640, tid);
  };
  auto stA = [&](int k, int b) {
    stage2<DT, 32, 32, 40>(eptr<DT>(Em, (long)k * 1024), bM[b], bM[b] + 1280, tid);
    stage2<DT, 32, 16, 24>(eptr<DT>(Fm, (long)k * 512), bM[b] + 2560, bM[b] + 3328, tid);
    stage1<DT, 16, 32, 40>(eptr<DT>(Gm, (long)k * 512), bO[b], tid);
  };

  short8 Xhi, Xlo;
  {
    const float* xp = xin + ((size_t)ch * SROWS + row) * 32 + quad * 8;
#pragma unroll
    for (int j = 0; j < 8; ++j) {
      float v = xp[j];
      unsigned short h = bf16u(v);
      Xhi[j] = (short)h;
      Xlo[j] = (short)bf16u(v - bf2f(h));
    }
  }
  stC(s, 0);
  UL<DT, 0> up;
  up.fetch(U, nullptr, row, s, qq);
  __syncthreads();

  f32x4 aX[2];
#pragma unroll 2
  for (int t = 0; t < CHS; ++t) {
    const int k = s + t, buf = t & 1;
    if (t < CHS - 1) stC(k + 1, buf ^ 1);
    short8 uh, ul;
    up.get(uh, ul);
    if (t < CHS - 1) up.fetch(U, nullptr, row, k + 1, qq);
    const f32x4 z4 = {0.f, 0.f, 0.f, 0.f};
    const short8 cf = ldfrag32(bO[buf], lane, 0);
    f32x4 ya = MFMA16(Xhi, cf, z4);
    ya = MFMA16(Xlo, cf, ya);
    const short8 df = ldfrag16(bO[buf] + 640, lane, 0);
    ya = MFMA16(uh, df, ya);
    if constexpr (DT) ya = MFMA16(ul, df, ya);
    const float bv = ldbias<DT>(biasv, k * 16 + cidx);
    {
      const size_t obase = (size_t)(tile * 64 + w * 16 + quad * 4) * 8192 + (size_t)k * 16 + cidx;
      if constexpr (DT == 0) {
        short* o = (short*)out;
#pragma unroll
        for (int r = 0; r < 4; ++r) o[obase + (size_t)r * 8192] = (short)bf16u(ya[r] + bv);
      } else {
        float* o = (float*)out;
#pragma unroll
        for (int r = 0; r < 4; ++r) o[obase + (size_t)r * 8192] = ya[r] + bv;
      }
    }
    step_state<DT>(Xhi, Xlo, uh, ul, bM[buf], bM[buf] + 1280, bM[buf] + 2560, bM[buf] + 3328,
                   aX, lane);
    twr(aX, T[w], lane);
    trd(T[w], lane, Xhi, Xlo);
    __syncthreads();
  }

  short8 Zhi, Zlo;
  {
    const float* zp = zin + ((size_t)ch * SROWS + row) * 32 + quad * 8;
#pragma unroll
    for (int j = 0; j < 8; ++j) {
      float v = zp[j];
      unsigned short h = bf16u(v);
      Zhi[j] = (short)h;
      Zlo[j] = (short)bf16u(v - bf2f(h));
    }
  }
  stA(s + CHS - 1, 0);
  up.fetch(U, nullptr, row, s + CHS - 1, qq);
  __syncthreads();

  f32x4 aZ[2];
#pragma unroll 2
  for (int t = 0; t < CHS; ++t) {
    const int k = s + CHS - 1 - t, buf = t & 1;
    if (t < CHS - 1) stA(k - 1, buf ^ 1);
    short8 uh, ul;
    up.get(uh, ul);
    if (t < CHS - 1) up.fetch(U, nullptr, row, k - 1, qq);
    const f32x4 z4 = {0.f, 0.f, 0.f, 0.f};
    const short8 gf = ldfrag32(bO[buf], lane, 0);
    f32x4 ya = MFMA16(Zhi, gf, z4);
    ya = MFMA16(Zlo, gf, ya);
    {
      const size_t obase = (size_t)(tile * 64 + w * 16 + quad * 4) * 8192 + (size_t)k * 16 + cidx;
      if constexpr (DT == 0) {
        short* o = (short*)out;
#pragma unroll
        for (int r = 0; r < 4; ++r) {
          const float c = bf2f((unsigned short)o[obase + (size_t)r * 8192]);
          o[obase + (size_t)r * 8192] = (short)bf16u(c + ya[r]);
        }
      } else {
        float* o = (float*)out;
#pragma unroll
        for (int r = 0; r < 4; ++r) o[obase + (size_t)r * 8192] += ya[r];
      }
    }
    step_state<DT>(Zhi, Zlo, uh, ul, bM[buf], bM[buf] + 1280, bM[buf] + 2560, bM[buf] + 3328,
                   aZ, lane);
    twr(aZ, T[w], lane);
    trd(T[w], lane, Zhi, Zlo);
    __syncthreads();
  }
}

extern "C" void kernel_launch(void* const* d_in, const int* in_sizes, int n_in,
                              void* d_out, int out_size, void* d_ws, size_t ws_size,
                              hipStream_t stream) {
  (void)in_sizes; (void)n_in; (void)out_size;
  const void* U = d_in[0];
  const void* A = d_in[1];
  const void* B = d_in[2];
  const void* C = d_in[3];
  const void* D = d_in[4];
  const void* E = d_in[5];
  const void* F = d_in[6];
  const void* G = d_in[7];
  const void* bias = d_in[8];

  constexpr size_t SC1 = (size_t)NCH * SROWS * 32;
  constexpr size_t BLOBS = (size_t)512 * 8192 * 2 + (size_t)512 * 2048 * 2;
  constexpr size_t UBB = (size_t)BATCH * 1024 * 32;
  constexpr size_t NEED1 = 1024 + BLOBS + SC1 * 8;
  constexpr size_t NEED2 = NEED1 + UBB;
  const int mode = (ws_size >= NEED2) ? 2 : (ws_size >= NEED1 ? 1 : 0);

  char* base = (char*)d_ws;
  int* flag = (int*)base;
  short* ABb = (short*)(base + 1024);
  short* EFb = ABb + (size_t)512 * 4096;
  short* CDb = EFb + (size_t)512 * 4096;
  short* Gb = CDb + (size_t)512 * 1024;
  float* Sc = (mode >= 1) ? (float*)(Gb + (size_t)512 * 1024) : (float*)(base + 1024);
  float* Sa = Sc + SC1;
  short* Ub = (short*)(Sa + SC1);

  k_detect<<<1, 64, 0, stream>>>((const unsigned short*)U, flag);
  if (mode >= 1) {
    k_prep<0><<<512, 256, 0, stream>>>(flag, A, B, C, D, E, F, G, ABb, EFb, CDb, Gb);
    k_prep<1><<<512, 256, 0, stream>>>(flag, A, B, C, D, E, F, G, ABb, EFb, CDb, Gb);
  }
  if (mode == 2) k_prepU<<<16384, 256, 0, stream>>>(flag, (const float*)U, Ub);

  if (mode >= 1) {
    k1_dual<0, 1><<<dim3(NCH, 33), 256, 0, stream>>>(flag, U, ABb, EFb, Ub, Sc, Sa);
    if (mode == 2)
      k1_dual<1, 2><<<dim3(NCH, 33), 256, 0, stream>>>(flag, U, ABb, EFb, Ub, Sc, Sa);
    else
      k1_dual<1, 1><<<dim3(NCH, 33), 256, 0, stream>>>(flag, U, ABb, EFb, Ub, Sc, Sa);
    k2_comb<<<dim3(BATCH / 8, 2), 256, 0, stream>>>(Sc, Sa);
    k3_dual<0, 1><<<dim3(NCH, 32), 256, 0, stream>>>(flag, U, bias, ABb, EFb, CDb, Gb, Ub,
                                                     Sc, Sa, d_out);
    if (mode == 2)
      k3_dual<1, 2><<<dim3(NCH, 32), 256, 0, stream>>>(flag, U, bias, ABb, EFb, CDb, Gb, Ub,
                                                       Sc, Sa, d_out);
    else
      k3_dual<1, 1><<<dim3(NCH, 32), 256, 0, stream>>>(flag, U, bias, ABb, EFb, CDb, Gb, Ub,
                                                       Sc, Sa, d_out);
  } else {
    k1_scan0<0><<<dim3(NCH, 65), 256, 0, stream>>>(flag, U, A, B, E, F, Sc, Sa);
    k1_scan0<1><<<dim3(NCH, 65), 256, 0, stream>>>(flag, U, A, B, E, F, Sc, Sa);
    k2_comb<<<dim3(BATCH / 8, 2), 256, 0, stream>>>(Sc, Sa);
    k3_legacy<0><<<dim3(NCH, 64), 256, 0, stream>>>(flag, U, A, B, C, D, E, F, G, bias,
                                                    Sc, Sa, d_out);
    k3_legacy<1><<<dim3(NCH, 64), 256, 0, stream>>>(flag, U, A, B, C, D, E, F, G, bias,
                                                    Sc, Sa, d_out);
  }
}

// Round 8
// 521.628 us; speedup vs baseline: 1.7479x; 1.2078x over previous
//
#include <hip/hip_runtime.h>

// SemiseparableLayer on MI355X (gfx950) — v9: pairwise stage composition (32 -> 16 iters).
// v8 evidence: ~8K cyc FIXED overhead per scan iteration (latency/barrier/transpose),
// insensitive to ILP and occupancy. v9 halves the iteration count instead:
//   x_{k+2} = (A1 A0) x + [A1 B0 | B1] u'      (u' = 32 contiguous u elements)
//   y_even  = C0 x + [D0|0] u'                 y_odd = (C1 A0) x + [C1 B0 | D1] u'
//   z_out   = (E0 E1) z + [F0 | E0 F1] u'      y_odd = G1 z ; y_even = (G0 E1) z + [0|G0 F1] u'
// k_prep_pair composes these in fp32 from ORIGINAL-precision inputs -> hi/lo bf16 blobs in
// the verified stride-40 layout. Scan loops are v8-dual verbatim otherwise: same staging
// (global_load_lds), same UL/Ub addressing (group g=4p+quad), same twr/trd, same
// first/second-touch out protocol (threshold t<8), same thread ownership. k2 unchanged.
// Mode 0 fallback = v8's single-stage kernels from original inputs.

#define BATCH 4096
#define NCH   16
#define CHS   32
#define NPAIR 16
#define SROWS (BATCH + 32)
#define TSTR  36

typedef __attribute__((ext_vector_type(8))) short short8;
typedef __attribute__((ext_vector_type(4))) float f32x4;
typedef short8 __attribute__((may_alias)) short8a;
typedef f32x4 __attribute__((may_alias)) f32x4a;
typedef unsigned __attribute__((may_alias)) uinta;

#define MFMA16(a, b, c) __builtin_amdgcn_mfma_f32_16x16x32_bf16(a, b, c, 0, 0, 0)

__device__ __forceinline__ unsigned short bf16u(float x) {
  unsigned u = __builtin_bit_cast(unsigned, x);
  u += 0x7fffu + ((u >> 16) & 1u);
  return (unsigned short)(u >> 16);
}
__device__ __forceinline__ float bf2f(unsigned short u) {
  return __builtin_bit_cast(float, ((unsigned)u) << 16);
}
__device__ __forceinline__ unsigned pk2(float a, float b) {
  return (unsigned)bf16u(a) | (((unsigned)bf16u(b)) << 16);
}
template <int DT>
__device__ __forceinline__ const void* eptr(const void* b, long e) {
  return (const char*)b + e * (DT ? 4 : 2);
}

// ---------------- async global->LDS blob staging ----------------
__device__ __forceinline__ void gload16(const void* g, void* lds) {
  __builtin_amdgcn_global_load_lds((const __attribute__((address_space(1))) void*)g,
                                   (__attribute__((address_space(3))) void*)lds, 16, 0, 0);
}
template <int NCHUNK>
__device__ __forceinline__ void stage_blobN(const short* g, short* lds, int w, int lane) {
  for (int c = w; c < NCHUNK; c += 4)
    gload16((const char*)g + c * 1024 + lane * 16, (char*)lds + c * 1024);
}

// ---------------- converting stagers (mode 0 fallback; verified) ----------------
template <int DT, int ROWS, int COLS, int PSTR>
__device__ __forceinline__ void stage2(const void* gp, short* hi, short* lo, int tid) {
  if constexpr (DT == 0) {
    const uinta* gu = (const uinta*)gp;
    for (int i = tid; i < ROWS * COLS / 2; i += 256) {
      int r = i / (COLS / 2), c = i - r * (COLS / 2);
      ((uinta*)(hi + r * PSTR))[c] = gu[i];
    }
  } else {
    const float* gf = (const float*)gp;
    for (int i = tid; i < ROWS * COLS; i += 256) {
      int r = i / COLS, c = i - r * COLS;
      float v = gf[i];
      unsigned short h = bf16u(v);
      hi[r * PSTR + c] = (short)h;
      lo[r * PSTR + c] = (short)bf16u(v - bf2f(h));
    }
  }
}
template <int DT, int ROWS, int COLS, int PSTR>
__device__ __forceinline__ void stage1(const void* gp, short* hi, int tid) {
  if constexpr (DT == 0) {
    const uinta* gu = (const uinta*)gp;
    for (int i = tid; i < ROWS * COLS / 2; i += 256) {
      int r = i / (COLS / 2), c = i - r * (COLS / 2);
      ((uinta*)(hi + r * PSTR))[c] = gu[i];
    }
  } else {
    const float* gf = (const float*)gp;
    for (int i = tid; i < ROWS * COLS; i += 256) {
      int r = i / COLS, c = i - r * COLS;
      hi[r * PSTR + c] = (short)bf16u(gf[i]);
    }
  }
}

// ---------------- fragment loaders (verified) ----------------
__device__ __forceinline__ short8 ldfrag32(const short* l, int lane, int nbase) {
  int n = nbase + (lane & 15), q = lane >> 4;
  return *(const short8a*)(l + n * 40 + q * 8);
}
__device__ __forceinline__ short8 ldfrag16(const short* l, int lane, int nbase) {
  int n = nbase + (lane & 15), q = lane >> 4;
  short8 z = {};
  if (q < 2) z = *(const short8a*)(l + n * 24 + q * 8);
  return z;
}

__device__ __forceinline__ void twr(const f32x4* acc, float* T, int lane) {
  const int c = lane & 15, q = lane >> 4;
#pragma unroll
  for (int h = 0; h < 2; ++h)
#pragma unroll
    for (int r = 0; r < 4; ++r) T[(q * 4 + r) * TSTR + h * 16 + c] = acc[h][r];
}
__device__ __forceinline__ void trd(const float* T, int lane, short8& hi, short8& lo) {
  const int m = lane & 15, q = lane >> 4;
  const float* p = T + m * TSTR + q * 8;
#pragma unroll
  for (int j = 0; j < 8; ++j) {
    float v = p[j];
    unsigned short h = bf16u(v);
    hi[j] = (short)h;
    lo[j] = (short)bf16u(v - bf2f(h));
  }
}

// ---------------- u loaders ----------------
template <int DT> struct URaw;
template <> struct URaw<0> { short8 s; };
template <> struct URaw<1> { f32x4 a, b; };

template <int DT>
__device__ __forceinline__ URaw<DT> ldu_raw(const void* U, size_t off) {
  URaw<DT> r;
  if constexpr (DT == 0) {
    r.s = *(const short8a*)((const short*)U + off);
  } else {
    const f32x4a* p = (const f32x4a*)((const float*)U + off);
    r.a = p[0];
    r.b = p[1];
  }
  return r;
}
template <int DT>
__device__ __forceinline__ void u_cvt(const URaw<DT>& r, short8& uhi, short8& ulo) {
  if constexpr (DT == 0) {
    uhi = r.s;
    ulo = short8{};
  } else {
#pragma unroll
    for (int j = 0; j < 4; ++j) {
      float v = r.a[j];
      unsigned short h = bf16u(v);
      uhi[j] = (short)h;
      ulo[j] = (short)bf16u(v - bf2f(h));
    }
#pragma unroll
    for (int j = 0; j < 4; ++j) {
      float v = r.b[j];
      unsigned short h = bf16u(v);
      uhi[4 + j] = (short)h;
      ulo[4 + j] = (short)bf16u(v - bf2f(h));
    }
  }
}
template <int DT, int MODE> struct UL {
  URaw<DT> r;
  __device__ __forceinline__ void fetch(const void* U, const short*, size_t row, int k, int qq) {
    r = ldu_raw<DT>(U, row * 8192 + (size_t)k * 16 + qq * 8);
  }
  __device__ __forceinline__ void fetchg(const void* U, const short*, size_t row, int g) {
    r = ldu_raw<DT>(U, row * 8192 + (size_t)g * 8);
  }
  __device__ __forceinline__ void get(short8& hi, short8& lo) const { u_cvt<DT>(r, hi, lo); }
};
template <> struct UL<1, 2> {  // preconverted Ub: group g -> {hi8, lo8}
  short8 h, l;
  __device__ __forceinline__ void fetch(const void*, const short* Ub, size_t row, int k, int qq) {
    const short* p = Ub + (row * 1024 + (size_t)k * 2 + qq) * 16;
    h = *(const short8a*)p;
    l = *(const short8a*)(p + 8);
  }
  __device__ __forceinline__ void fetchg(const void*, const short* Ub, size_t row, int g) {
    const short* p = Ub + (row * 1024 + (size_t)g) * 16;
    h = *(const short8a*)p;
    l = *(const short8a*)(p + 8);
  }
  __device__ __forceinline__ void get(short8& hi, short8& lo) const { hi = h; lo = l; }
};

template <int DT>
__device__ __forceinline__ float ldbias(const void* b, int i) {
  if constexpr (DT == 0) return bf2f((unsigned short)((const short*)b)[i]);
  else return ((const float*)b)[i];
}

// mode-0 single-stage step (verified)
template <int DT>
__device__ __forceinline__ void step_state(const short8& Xhi, const short8& Xlo,
                                           const short8& uhi, const short8& ulo,
                                           const short* Mhi, const short* Mlo,
                                           const short* Bhi, const short* Blo,
                                           f32x4* out, int lane) {
#pragma unroll
  for (int h = 0; h < 2; ++h) {
    const f32x4 z4 = {0.f, 0.f, 0.f, 0.f};
    short8 bA = ldfrag32(Mhi, lane, h * 16);
    f32x4 ax = MFMA16(Xhi, bA, z4);
    ax = MFMA16(Xlo, bA, ax);
    short8 bB = ldfrag16(Bhi, lane, h * 16);
    ax = MFMA16(uhi, bB, ax);
    if constexpr (DT) {
      short8 bAl = ldfrag32(Mlo, lane, h * 16);
      ax = MFMA16(Xhi, bAl, ax);
      ax = MFMA16(ulo, bB, ax);
      short8 bBl = ldfrag16(Blo, lane, h * 16);
      ax = MFMA16(uhi, bBl, ax);
    }
    out[h] = ax;
  }
}
// pair step, dual tile: blob = A'hi|A'lo|B'hi|B'lo (all 32x32, stride 40)
template <int DT>
__device__ __forceinline__ void step_pair32(const short8& X0h, const short8& X0l,
                                            const short8& u0h, const short8& u0l,
                                            const short8& X1h, const short8& X1l,
                                            const short8& u1h, const short8& u1l,
                                            const short* blob, f32x4* o0, f32x4* o1, int lane) {
  const short* Ah = blob;
  const short* Al = blob + 1280;
  const short* Bh = blob + 2560;
  const short* Bl = blob + 3840;
#pragma unroll
  for (int h = 0; h < 2; ++h) {
    const f32x4 z4 = {0.f, 0.f, 0.f, 0.f};
    short8 bA = ldfrag32(Ah, lane, h * 16);
    f32x4 a0 = MFMA16(X0h, bA, z4);
    f32x4 a1 = MFMA16(X1h, bA, z4);
    a0 = MFMA16(X0l, bA, a0);
    a1 = MFMA16(X1l, bA, a1);
    short8 bB = ldfrag32(Bh, lane, h * 16);
    a0 = MFMA16(u0h, bB, a0);
    a1 = MFMA16(u1h, bB, a1);
    short8 bAl = ldfrag32(Al, lane, h * 16);
    a0 = MFMA16(X0h, bAl, a0);
    a1 = MFMA16(X1h, bAl, a1);
    short8 bBl = ldfrag32(Bl, lane, h * 16);
    a0 = MFMA16(u0h, bBl, a0);
    a1 = MFMA16(u1h, bBl, a1);
    if constexpr (DT) {
      a0 = MFMA16(u0l, bB, a0);
      a1 = MFMA16(u1l, bB, a1);
    }
    o0[h] = a0;
    o1[h] = a1;
  }
}

// ---------------- dtype detector ----------------
__global__ void k_detect(const unsigned short* __restrict__ U16, int* __restrict__ flag) {
  int lane = threadIdx.x;
  int bad = 0;
  for (int i = lane; i < 512; i += 64) {
    int e = (U16[i] >> 7) & 0xFF;
    bad += ((e > 134) || (e < 96 && e != 0)) ? 1 : 0;
  }
#pragma unroll
  for (int s = 32; s; s >>= 1) bad += __shfl_xor(bad, s);
  if (lane == 0) *flag = (bad > 48) ? 1 : 0;
}

// ---------------- k_prep_pair: compose 2 stages -> hi/lo blobs ----------------
// ABp[p] (10240B): A'hi[32][40] A'lo B'hi[32][40] B'lo   (A'=A1A0, B'=[A1B0|B1])
// EFp[p]: E'hi E'lo F'hi F'lo                            (E'=E0E1, F'=[F0|E0F1])
// Ycp[p] (5120B, hi-only): Ce[16][40] De Co Do           (Ce=C0, De=[D0|0], Co=C1A0, Do=[C1B0|D1])
// Yap[p]: Ga Gb Gu pad                                   (Ga=G1, Gb=G0E1, Gu=[0|G0F1])
template <int DT>
__global__ __launch_bounds__(256) void k_prep_pair(
    const int* __restrict__ flagp,
    const void* __restrict__ Am, const void* __restrict__ Bm, const void* __restrict__ Cm,
    const void* __restrict__ Dm, const void* __restrict__ Em, const void* __restrict__ Fm,
    const void* __restrict__ Gm,
    short* __restrict__ ABp, short* __restrict__ EFp, short* __restrict__ Ycp,
    short* __restrict__ Yap) {
  if (*flagp != DT) return;
  const int p = blockIdx.x, tid = threadIdx.x;
  const long k0 = 2 * p, k1s = 2 * p + 1;
  __shared__ float A0[1024], A1[1024], B0[512], B1[512], C0[512], C1[512];
  __shared__ float D0[256], D1[256], E0[1024], E1[1024], F0[512], F1[512];
  __shared__ float G0[512], G1[512];
  auto ldm = [&](float* dst, const void* src, long base, int n) {
    for (int i = tid; i < n; i += 256)
      dst[i] = (DT == 0) ? bf2f(((const unsigned short*)src)[base + i])
                         : ((const float*)src)[base + i];
  };
  ldm(A0, Am, k0 * 1024, 1024);
  ldm(A1, Am, k1s * 1024, 1024);
  ldm(B0, Bm, k0 * 512, 512);
  ldm(B1, Bm, k1s * 512, 512);
  ldm(C0, Cm, k0 * 512, 512);
  ldm(C1, Cm, k1s * 512, 512);
  ldm(D0, Dm, k0 * 256, 256);
  ldm(D1, Dm, k1s * 256, 256);
  ldm(E0, Em, k0 * 1024, 1024);
  ldm(E1, Em, k1s * 1024, 1024);
  ldm(F0, Fm, k0 * 512, 512);
  ldm(F1, Fm, k1s * 512, 512);
  ldm(G0, Gm, k0 * 512, 512);
  ldm(G1, Gm, k1s * 512, 512);
  __syncthreads();
  short* ab = ABp + (size_t)p * 5120;
  short* ef = EFp + (size_t)p * 5120;
  short* yc = Ycp + (size_t)p * 2560;
  short* ya = Yap + (size_t)p * 2560;
  auto put2 = [&](short* hi, short* lo, int off, float v) {
    unsigned short h = bf16u(v);
    hi[off] = (short)h;
    lo[off] = (short)bf16u(v - bf2f(h));
  };
  for (int i = tid; i < 1024; i += 256) {
    const int n = i >> 5, m = i & 31;
    float a = 0.f, e = 0.f;
#pragma unroll
    for (int k = 0; k < 32; ++k) {
      a += A1[n * 32 + k] * A0[k * 32 + m];
      e += E0[n * 32 + k] * E1[k * 32 + m];
    }
    put2(ab, ab + 1280, n * 40 + m, a);
    put2(ef, ef + 1280, n * 40 + m, e);
    float bv, fv;
    if (m < 16) {
      float s = 0.f;
#pragma unroll
      for (int k = 0; k < 32; ++k) s += A1[n * 32 + k] * B0[k * 16 + m];
      bv = s;
      fv = F0[n * 16 + m];
    } else {
      const int mm = m - 16;
      bv = B1[n * 16 + mm];
      float s = 0.f;
#pragma unroll
      for (int k = 0; k < 32; ++k) s += E0[n * 32 + k] * F1[k * 16 + mm];
      fv = s;
    }
    put2(ab + 2560, ab + 3840, n * 40 + m, bv);
    put2(ef + 2560, ef + 3840, n * 40 + m, fv);
  }
  for (int i = tid; i < 512; i += 256) {
    const int n = i >> 5, m = i & 31;
    yc[n * 40 + m] = (short)bf16u(C0[n * 32 + m]);
    yc[640 + n * 40 + m] = (m < 16) ? (short)bf16u(D0[n * 16 + m]) : (short)0;
    float co = 0.f;
#pragma unroll
    for (int k = 0; k < 32; ++k) co += C1[n * 32 + k] * A0[k * 32 + m];
    yc[1280 + n * 40 + m] = (short)bf16u(co);
    float dov;
    if (m < 16) {
      float s = 0.f;
#pragma unroll
      for (int k = 0; k < 32; ++k) s += C1[n * 32 + k] * B0[k * 16 + m];
      dov = s;
    } else {
      dov = D1[n * 16 + (m - 16)];
    }
    yc[1920 + n * 40 + m] = (short)bf16u(dov);
    ya[n * 40 + m] = (short)bf16u(G1[n * 32 + m]);
    float gb = 0.f;
#pragma unroll
    for (int k = 0; k < 32; ++k) gb += G0[n * 32 + k] * E1[k * 32 + m];
    ya[640 + n * 40 + m] = (short)bf16u(gb);
    float gu = 0.f;
    if (m >= 16) {
#pragma unroll
      for (int k = 0; k < 32; ++k) gu += G0[n * 32 + k] * F1[k * 16 + (m - 16)];
    }
    ya[1280 + n * 40 + m] = (short)bf16u(gu);
    ya[1920 + n * 40 + m] = 0;
  }
}

__global__ __launch_bounds__(256) void k_prepU(const int* __restrict__ flagp,
                                               const float* __restrict__ Uf,
                                               short* __restrict__ Ub) {
  if (*flagp != 1) return;
  const size_t i = (size_t)blockIdx.x * 256 + threadIdx.x;
  const f32x4a* p = (const f32x4a*)(Uf + i * 8);
  f32x4 a = p[0], b = p[1];
  short8 hi, lo;
#pragma unroll
  for (int j = 0; j < 4; ++j) {
    unsigned short h = bf16u(a[j]);
    hi[j] = (short)h;
    lo[j] = (short)bf16u(a[j] - bf2f(h));
  }
#pragma unroll
  for (int j = 0; j < 4; ++j) {
    unsigned short h = bf16u(b[j]);
    hi[4 + j] = (short)h;
    lo[4 + j] = (short)bf16u(b[j] - bf2f(h));
  }
  *(short8a*)(Ub + i * 16) = hi;
  *(short8a*)(Ub + i * 16 + 8) = lo;
}

// ---------------- K1 pair dual-tile (mode >= 1): grid (NCH, 33) ----------------
template <int DT, int MODE>
__global__ __launch_bounds__(256, 2) void k1_pair(
    const int* __restrict__ flagp, const void* __restrict__ U,
    const short* __restrict__ ABp, const short* __restrict__ EFp,
    const short* __restrict__ Ub,
    float* __restrict__ Sc, float* __restrict__ Sa) {
  if (*flagp != DT) return;
  const int ch = blockIdx.x, y = blockIdx.y;
  const int tile0 = (y < 32) ? 2 * y : 64, tile1 = (y < 32) ? 2 * y + 1 : 64;
  const bool id0 = (tile0 == 64), id1 = (tile1 == 64);
  const int tid = threadIdx.x, lane = tid & 63, w = tid >> 6;
  const int bp = ch * NPAIR;
  __shared__ __align__(16) short bAB[2][5120];
  __shared__ __align__(16) short bEF[2][5120];
  __shared__ __align__(16) float T[4][16 * TSTR];

  short8 X0h = {}, X0l = {}, Z0h = {}, Z0l = {};
  short8 X1h = {}, X1l = {}, Z1h = {}, Z1l = {};
  if (id0 || id1) {
    const int m = lane & 15, q = lane >> 4;
    short8 id = {};
#pragma unroll
    for (int j = 0; j < 8; ++j) id[j] = ((q * 8 + j) == (w * 16 + m)) ? (short)0x3F80 : (short)0;
    if (id0) { X0h = id; Z0h = id; }
    if (id1) { X1h = id; Z1h = id; }
  }

  stage_blobN<10>(ABp + (size_t)bp * 5120, bAB[0], w, lane);
  stage_blobN<10>(EFp + (size_t)(bp + NPAIR - 1) * 5120, bEF[0], w, lane);

  const size_t row0 = (size_t)(id0 ? 0 : (tile0 * 64 + w * 16 + (lane & 15)));
  const size_t row1 = (size_t)(id1 ? 0 : (tile1 * 64 + w * 16 + (lane & 15)));
  const int quad = lane >> 4;
  UL<DT, MODE> uc0, ua0, uc1, ua1;
  if (!id0) {
    uc0.fetchg(U, Ub, row0, bp * 4 + quad);
    ua0.fetchg(U, Ub, row0, (bp + NPAIR - 1) * 4 + quad);
  }
  if (!id1) {
    uc1.fetchg(U, Ub, row1, bp * 4 + quad);
    ua1.fetchg(U, Ub, row1, (bp + NPAIR - 1) * 4 + quad);
  }
  __syncthreads();

  f32x4 aX0[2], aZ0[2], aX1[2], aZ1[2];
#pragma unroll 2
  for (int t = 0; t < NPAIR; ++t) {
    const int pc = bp + t, pa = bp + NPAIR - 1 - t, buf = t & 1;
    if (t < NPAIR - 1) {
      stage_blobN<10>(ABp + (size_t)(pc + 1) * 5120, bAB[buf ^ 1], w, lane);
      stage_blobN<10>(EFp + (size_t)(pa - 1) * 5120, bEF[buf ^ 1], w, lane);
    }
    short8 c0h = {}, c0l = {}, a0h = {}, a0l = {};
    short8 c1h = {}, c1l = {}, a1h = {}, a1l = {};
    if (!id0) {
      uc0.get(c0h, c0l);
      ua0.get(a0h, a0l);
      if (t < NPAIR - 1) {
        uc0.fetchg(U, Ub, row0, (pc + 1) * 4 + quad);
        ua0.fetchg(U, Ub, row0, (pa - 1) * 4 + quad);
      }
    }
    if (!id1) {
      uc1.get(c1h, c1l);
      ua1.get(a1h, a1l);
      if (t < NPAIR - 1) {
        uc1.fetchg(U, Ub, row1, (pc + 1) * 4 + quad);
        ua1.fetchg(U, Ub, row1, (pa - 1) * 4 + quad);
      }
    }
    step_pair32<DT>(X0h, X0l, c0h, c0l, X1h, X1l, c1h, c1l, bAB[buf], aX0, aX1, lane);
    step_pair32<DT>(Z0h, Z0l, a0h, a0l, Z1h, Z1l, a1h, a1l, bEF[buf], aZ0, aZ1, lane);
    twr(aX0, T[w], lane);
    trd(T[w], lane, X0h, X0l);
    twr(aZ0, T[w], lane);
    trd(T[w], lane, Z0h, Z0l);
    twr(aX1, T[w], lane);
    trd(T[w], lane, X1h, X1l);
    twr(aZ1, T[w], lane);
    trd(T[w], lane, Z1h, Z1l);
    __syncthreads();
  }

  const int n = lane & 15, q = lane >> 4;
  if (!id0 || w < 2) {
    const int grow = tile0 * 64 + w * 16;
#pragma unroll
    for (int h = 0; h < 2; ++h)
#pragma unroll
      for (int r = 0; r < 4; ++r) {
        const int m = q * 4 + r, col = h * 16 + n;
        const size_t off = ((size_t)ch * SROWS + grow + m) * 32 + col;
        Sc[off] = aX0[h][r];
        Sa[off] = aZ0[h][r];
      }
  }
  if (!id1 || w < 2) {
    const int grow = tile1 * 64 + w * 16;
#pragma unroll
    for (int h = 0; h < 2; ++h)
#pragma unroll
      for (int r = 0; r < 4; ++r) {
        const int m = q * 4 + r, col = h * 16 + n;
        const size_t off = ((size_t)ch * SROWS + grow + m) * 32 + col;
        Sc[off] = aX1[h][r];
        Sa[off] = aZ1[h][r];
      }
  }
}

// ---------------- K2 (v1 verbatim) ----------------
__global__ __launch_bounds__(256) void k2_comb(float* __restrict__ Sc, float* __restrict__ Sa) {
  const int dir = blockIdx.y;
  const int r = threadIdx.x >> 5, j = threadIdx.x & 31;
  const int row = blockIdx.x * 8 + r;
  float* S = dir ? Sa : Sc;
  __shared__ float P[32][33];
  __shared__ float xs[8][33];
  float x = 0.f;
  for (int it = 0; it < NCH; ++it) {
    const int ch = dir ? (NCH - 1 - it) : it;
    const size_t base = ((size_t)ch * SROWS + row) * 32 + j;
    const float s_local = S[base];
    for (int i = threadIdx.x; i < 1024; i += 256)
      P[i >> 5][i & 31] = S[((size_t)ch * SROWS + BATCH + (i >> 5)) * 32 + (i & 31)];
    xs[r][j] = x;
    __syncthreads();
    S[base] = x;
    float acc = s_local;
#pragma unroll
    for (int m = 0; m < 32; ++m) acc += xs[r][m] * P[m][j];
    x = acc;
    __syncthreads();
  }
}

// ---------------- K3 pair dual-tile merged (mode >= 1): grid (NCH, 32) ----------------
template <int DT, int MODE>
__global__ __launch_bounds__(256, 2) void k3_pair(
    const int* __restrict__ flagp, const void* __restrict__ U, const void* __restrict__ biasv,
    const short* __restrict__ ABp, const short* __restrict__ EFp,
    const short* __restrict__ Ycp, const short* __restrict__ Yap,
    const short* __restrict__ Ub,
    const float* __restrict__ xin, const float* __restrict__ zin,
    void* __restrict__ out) {
  if (*flagp != DT) return;
  const int ch = blockIdx.x, tile0 = blockIdx.y * 2, tile1 = tile0 + 1;
  const int tid = threadIdx.x, lane = tid & 63, w = tid >> 6;
  const int bp = ch * NPAIR;
  __shared__ __align__(16) short bAB[2][5120];
  __shared__ __align__(16) short bEF[2][5120];
  __shared__ __align__(16) short bYc[2][2560];
  __shared__ __align__(16) short bYa[2][2560];
  __shared__ __align__(16) float T[4][16 * TSTR];

  const int cidx = lane & 15, quad = lane >> 4;
  const size_t row0 = (size_t)(tile0 * 64 + w * 16 + cidx);
  const size_t row1 = (size_t)(tile1 * 64 + w * 16 + cidx);

  short8 X0h, X0l, Z0h, Z0l, X1h, X1l, Z1h, Z1l;
  {
    auto ld8 = [&](const float* p, short8& hi, short8& lo) {
#pragma unroll
      for (int j = 0; j < 8; ++j) {
        float v = p[j];
        unsigned short h = bf16u(v);
        hi[j] = (short)h;
        lo[j] = (short)bf16u(v - bf2f(h));
      }
    };
    ld8(xin + ((size_t)ch * SROWS + row0) * 32 + quad * 8, X0h, X0l);
    ld8(zin + ((size_t)ch * SROWS + row0) * 32 + quad * 8, Z0h, Z0l);
    ld8(xin + ((size_t)ch * SROWS + row1) * 32 + quad * 8, X1h, X1l);
    ld8(zin + ((size_t)ch * SROWS + row1) * 32 + quad * 8, Z1h, Z1l);
  }

  stage_blobN<10>(ABp + (size_t)bp * 5120, bAB[0], w, lane);
  stage_blobN<5>(Ycp + (size_t)bp * 2560, bYc[0], w, lane);
  stage_blobN<10>(EFp + (size_t)(bp + NPAIR - 1) * 5120, bEF[0], w, lane);
  stage_blobN<5>(Yap + (size_t)(bp + NPAIR - 1) * 2560, bYa[0], w, lane);
  UL<DT, MODE> uc0, ua0, uc1, ua1;
  uc0.fetchg(U, Ub, row0, bp * 4 + quad);
  ua0.fetchg(U, Ub, row0, (bp + NPAIR - 1) * 4 + quad);
  uc1.fetchg(U, Ub, row1, bp * 4 + quad);
  ua1.fetchg(U, Ub, row1, (bp + NPAIR - 1) * 4 + quad);
  __syncthreads();

  f32x4 aX0[2], aZ0[2], aX1[2], aZ1[2];
#pragma unroll 2
  for (int t = 0; t < NPAIR; ++t) {
    const int pc = bp + t, pa = bp + NPAIR - 1 - t, buf = t & 1;
    if (t < NPAIR - 1) {
      stage_blobN<10>(ABp + (size_t)(pc + 1) * 5120, bAB[buf ^ 1], w, lane);
      stage_blobN<5>(Ycp + (size_t)(pc + 1) * 2560, bYc[buf ^ 1], w, lane);
      stage_blobN<10>(EFp + (size_t)(pa - 1) * 5120, bEF[buf ^ 1], w, lane);
      stage_blobN<5>(Yap + (size_t)(pa - 1) * 2560, bYa[buf ^ 1], w, lane);
    }
    short8 u0h, u0l, v0h, v0l, u1h, u1l, v1h, v1l;
    uc0.get(u0h, u0l);
    ua0.get(v0h, v0l);
    uc1.get(u1h, u1l);
    ua1.get(v1h, v1l);
    if (t < NPAIR - 1) {
      uc0.fetchg(U, Ub, row0, (pc + 1) * 4 + quad);
      ua0.fetchg(U, Ub, row0, (pa - 1) * 4 + quad);
      uc1.fetchg(U, Ub, row1, (pc + 1) * 4 + quad);
      ua1.fetchg(U, Ub, row1, (pa - 1) * 4 + quad);
    }
    const f32x4 z4 = {0.f, 0.f, 0.f, 0.f};
    const short8 ce = ldfrag32(bYc[buf], lane, 0);
    const short8 de = ldfrag32(bYc[buf] + 640, lane, 0);
    const short8 co = ldfrag32(bYc[buf] + 1280, lane, 0);
    const short8 dv = ldfrag32(bYc[buf] + 1920, lane, 0);
    const short8 ga = ldfrag32(bYa[buf], lane, 0);
    const short8 gb = ldfrag32(bYa[buf] + 640, lane, 0);
    const short8 gu = ldfrag32(bYa[buf] + 1280, lane, 0);

    auto ycalc = [&](const short8& Xh, const short8& Xl, const short8& uh, const short8& ul,
                     const short8& M, const short8& Du, f32x4& y) {
      y = MFMA16(Xh, M, z4);
      y = MFMA16(Xl, M, y);
      y = MFMA16(uh, Du, y);
      if constexpr (DT) y = MFMA16(ul, Du, y);
    };
    f32x4 yce0, yco0, yce1, yco1;
    ycalc(X0h, X0l, u0h, u0l, ce, de, yce0);
    ycalc(X0h, X0l, u0h, u0l, co, dv, yco0);
    ycalc(X1h, X1l, u1h, u1l, ce, de, yce1);
    ycalc(X1h, X1l, u1h, u1l, co, dv, yco1);
    f32x4 yza0 = MFMA16(Z0h, ga, z4);
    yza0 = MFMA16(Z0l, ga, yza0);
    f32x4 yzb0, yza1, yzb1;
    ycalc(Z0h, Z0l, v0h, v0l, gb, gu, yzb0);
    yza1 = MFMA16(Z1h, ga, z4);
    yza1 = MFMA16(Z1l, ga, yza1);
    ycalc(Z1h, Z1l, v1h, v1l, gb, gu, yzb1);

    const float bve = ldbias<DT>(biasv, (2 * pc) * 16 + cidx);
    const float bvo = ldbias<DT>(biasv, (2 * pc + 1) * 16 + cidx);
    auto store4 = [&](size_t off, const f32x4& yv, float badd) {
      if constexpr (DT == 0) {
        short* o = (short*)out;
#pragma unroll
        for (int r = 0; r < 4; ++r) o[off + (size_t)r * 8192] = (short)bf16u(yv[r] + badd);
      } else {
        float* o = (float*)out;
        *(uinta*)(o + off) = pk2(yv[0] + badd, yv[1] + badd);
        *(uinta*)(o + off + 2 * 8192) = pk2(yv[2] + badd, yv[3] + badd);
      }
    };
    auto fin4 = [&](size_t off, const f32x4& yv, float badd) {
      if constexpr (DT == 0) {
        short* o = (short*)out;
#pragma unroll
        for (int r = 0; r < 4; ++r) {
          const float c = bf2f((unsigned short)o[off + (size_t)r * 8192]);
          o[off + (size_t)r * 8192] = (short)bf16u(c + yv[r] + badd);
        }
      } else {
        float* o = (float*)out;
        const unsigned p0 = *(const uinta*)(o + off);
        const unsigned p1 = *(const uinta*)(o + off + 2 * 8192);
        o[off + 0 * 8192] = bf2f((unsigned short)(p0 & 0xffffu)) + yv[0] + badd;
        o[off + 1 * 8192] = bf2f((unsigned short)(p0 >> 16)) + yv[1] + badd;
        o[off + 2 * 8192] = bf2f((unsigned short)(p1 & 0xffffu)) + yv[2] + badd;
        o[off + 3 * 8192] = bf2f((unsigned short)(p1 >> 16)) + yv[3] + badd;
      }
    };
    auto emit = [&](int tile, const f32x4& ye, const f32x4& yo, const f32x4& za,
                    const f32x4& zb) {
      const size_t rbase = (size_t)(tile * 64 + w * 16 + quad * 4) * 8192;
      const size_t oce = rbase + (size_t)(2 * pc) * 16 + cidx;
      const size_t oco = rbase + (size_t)(2 * pc + 1) * 16 + cidx;
      const size_t oaa = rbase + (size_t)(2 * pa + 1) * 16 + cidx;
      const size_t oab = rbase + (size_t)(2 * pa) * 16 + cidx;
      if (t < NPAIR / 2) {
        store4(oce, ye, bve);
        store4(oco, yo, bvo);
        store4(oaa, za, 0.f);
        store4(oab, zb, 0.f);
      } else {
        fin4(oce, ye, bve);
        fin4(oco, yo, bvo);
        fin4(oaa, za, 0.f);
        fin4(oab, zb, 0.f);
      }
    };
    emit(tile0, yce0, yco0, yza0, yzb0);
    emit(tile1, yce1, yco1, yza1, yzb1);

    step_pair32<DT>(X0h, X0l, u0h, u0l, X1h, X1l, u1h, u1l, bAB[buf], aX0, aX1, lane);
    step_pair32<DT>(Z0h, Z0l, v0h, v0l, Z1h, Z1l, v1h, v1l, bEF[buf], aZ0, aZ1, lane);
    twr(aX0, T[w], lane);
    trd(T[w], lane, X0h, X0l);
    twr(aZ0, T[w], lane);
    trd(T[w], lane, Z0h, Z0l);
    twr(aX1, T[w], lane);
    trd(T[w], lane, X1h, X1l);
    twr(aZ1, T[w], lane);
    trd(T[w], lane, Z1h, Z1l);
    __syncthreads();
  }
}

// ---------------- mode-0 fallbacks (v6/v8 verbatim, from original inputs) ----------------
template <int DT>
__global__ __launch_bounds__(256, 4) void k1_scan0(
    const int* __restrict__ flagp, const void* __restrict__ U,
    const void* __restrict__ Am, const void* __restrict__ Bm,
    const void* __restrict__ Em, const void* __restrict__ Fm,
    float* __restrict__ Sc, float* __restrict__ Sa) {
  if (*flagp != DT) return;
  const int ch = blockIdx.x, tile = blockIdx.y;
  const bool ident = (tile == 64);
  const int tid = threadIdx.x, lane = tid & 63, w = tid >> 6;
  const int s = ch * CHS;
  __shared__ __align__(16) short bAB[2][4096];
  __shared__ __align__(16) short bEF[2][4096];
  __shared__ __align__(16) float T[4][16 * TSTR];

  short8 Xhi = {}, Xlo = {}, Zhi = {}, Zlo = {};
  if (ident) {
    const int m = lane & 15, q = lane >> 4;
    short8 id = {};
#pragma unroll
    for (int j = 0; j < 8; ++j) id[j] = ((q * 8 + j) == (w * 16 + m)) ? (short)0x3F80 : (short)0;
    Xhi = id; Zhi = id;
  }
  auto stAB = [&](int k, int b) {
    stage2<DT, 32, 32, 40>(eptr<DT>(Am, (long)k * 1024), bAB[b], bAB[b] + 1280, tid);
    stage2<DT, 32, 16, 24>(eptr<DT>(Bm, (long)k * 512), bAB[b] + 2560, bAB[b] + 3328, tid);
  };
  auto stEF = [&](int k, int b) {
    stage2<DT, 32, 32, 40>(eptr<DT>(Em, (long)k * 1024), bEF[b], bEF[b] + 1280, tid);
    stage2<DT, 32, 16, 24>(eptr<DT>(Fm, (long)k * 512), bEF[b] + 2560, bEF[b] + 3328, tid);
  };
  stAB(s, 0);
  stEF(s + CHS - 1, 0);
  const size_t row = (size_t)(ident ? 0 : (tile * 64 + w * 16 + (lane & 15)));
  const int qq = (lane >> 4) & 1;
  UL<DT, 0> upc, upa;
  if (!ident) {
    upc.fetch(U, nullptr, row, s, qq);
    upa.fetch(U, nullptr, row, s + CHS - 1, qq);
  }
  __syncthreads();
  f32x4 aX[2], aZ[2];
#pragma unroll 2
  for (int t = 0; t < CHS; ++t) {
    const int kc = s + t, ka = s + CHS - 1 - t, buf = t & 1;
    if (t < CHS - 1) {
      stAB(kc + 1, buf ^ 1);
      stEF(ka - 1, buf ^ 1);
    }
    short8 uch = {}, ucl = {}, uah = {}, ual = {};
    if (!ident) {
      upc.get(uch, ucl);
      upa.get(uah, ual);
      if (t < CHS - 1) {
        upc.fetch(U, nullptr, row, kc + 1, qq);
        upa.fetch(U, nullptr, row, ka - 1, qq);
      }
    }
    step_state<DT>(Xhi, Xlo, uch, ucl, bAB[buf], bAB[buf] + 1280, bAB[buf] + 2560,
                   bAB[buf] + 3328, aX, lane);
    step_state<DT>(Zhi, Zlo, uah, ual, bEF[buf], bEF[buf] + 1280, bEF[buf] + 2560,
                   bEF[buf] + 3328, aZ, lane);
    twr(aX, T[w], lane);
    trd(T[w], lane, Xhi, Xlo);
    twr(aZ, T[w], lane);
    trd(T[w], lane, Zhi, Zlo);
    __syncthreads();
  }
  if (!ident || w < 2) {
    const int grow = tile * 64 + w * 16;
#pragma unroll
    for (int h = 0; h < 2; ++h)
#pragma unroll
      for (int r = 0; r < 4; ++r) {
        const int m = (lane >> 4) * 4 + r, col = h * 16 + (lane & 15);
        const size_t off = ((size_t)ch * SROWS + grow + m) * 32 + col;
        Sc[off] = aX[h][r];
        Sa[off] = aZ[h][r];
      }
  }
}

template <int DT>
__global__ __launch_bounds__(256, 4) void k3_legacy(
    const int* __restrict__ flagp, const void* __restrict__ U,
    const void* __restrict__ Am, const void* __restrict__ Bm,
    const void* __restrict__ Cm, const void* __restrict__ Dm,
    const void* __restrict__ Em, const void* __restrict__ Fm,
    const void* __restrict__ Gm, const void* __restrict__ biasv,
    const float* __restrict__ xin, const float* __restrict__ zin,
    void* __restrict__ out) {
  if (*flagp != DT) return;
  const int ch = blockIdx.x, tile = blockIdx.y;
  const int tid = threadIdx.x, lane = tid & 63, w = tid >> 6;
  const int s = ch * CHS;
  __shared__ __align__(16) short bM[2][4096];
  __shared__ __align__(16) short bO[2][1024];
  __shared__ __align__(16) float T[4][16 * TSTR];
  const int cidx = lane & 15, quad = lane >> 4, qq = quad & 1;
  const size_t row = (size_t)(tile * 64 + w * 16 + cidx);
  auto stC = [&](int k, int b) {
    stage2<DT, 32, 32, 40>(eptr<DT>(Am, (long)k * 1024), bM[b], bM[b] + 1280, tid);
    stage2<DT, 32, 16, 24>(eptr<DT>(Bm, (long)k * 512), bM[b] + 2560, bM[b] + 3328, tid);
    stage1<DT, 16, 32, 40>(eptr<DT>(Cm, (long)k * 512), bO[b], tid);
    stage1<DT, 16, 16, 24>(eptr<DT>(Dm, (long)k * 256), bO[b] + 640, tid);
  };
  auto stA = [&](int k, int b) {
    stage2<DT, 32, 32, 40>(eptr<DT>(Em, (long)k * 1024), bM[b], bM[b] + 1280, tid);
    stage2<DT, 32, 16, 24>(eptr<DT>(Fm, (long)k * 512), bM[b] + 2560, bM[b] + 3328, tid);
    stage1<DT, 16, 32, 40>(eptr<DT>(Gm, (long)k * 512), bO[b], tid);
  };
  short8 Xhi, Xlo;
  {
    const float* xp = xin + ((size_t)ch * SROWS + row) * 32 + quad * 8;
#pragma unroll
    for (int j = 0; j < 8; ++j) {
      float v = xp[j];
      unsigned short h = bf16u(v);
      Xhi[j] = (short)h;
      Xlo[j] = (short)bf16u(v - bf2f(h));
    }
  }
  stC(s, 0);
  UL<DT, 0> up;
  up.fetch(U, nullptr, row, s, qq);
  __syncthreads();
  f32x4 aX[2];
#pragma unroll 2
  for (int t = 0; t < CHS; ++t) {
    const int k = s + t, buf = t & 1;
    if (t < CHS - 1) stC(k + 1, buf ^ 1);
    short8 uh, ul;
    up.get(uh, ul);
    if (t < CHS - 1) up.fetch(U, nullptr, row, k + 1, qq);
    const f32x4 z4 = {0.f, 0.f, 0.f, 0.f};
    const short8 cf = ldfrag32(bO[buf], lane, 0);
    f32x4 ya = MFMA16(Xhi, cf, z4);
    ya = MFMA16(Xlo, cf, ya);
    const short8 df = ldfrag16(bO[buf] + 640, lane, 0);
    ya = MFMA16(uh, df, ya);
    if constexpr (DT) ya = MFMA16(ul, df, ya);
    const float bv = ldbias<DT>(biasv, k * 16 + cidx);
    {
      const size_t obase = (size_t)(tile * 64 + w * 16 + quad * 4) * 8192 + (size_t)k * 16 + cidx;
      if constexpr (DT == 0) {
        short* o = (short*)out;
#pragma unroll
        for (int r = 0; r < 4; ++r) o[obase + (size_t)r * 8192] = (short)bf16u(ya[r] + bv);
      } else {
        float* o = (float*)out;
#pragma unroll
        for (int r = 0; r < 4; ++r) o[obase + (size_t)r * 8192] = ya[r] + bv;
      }
    }
    step_state<DT>(Xhi, Xlo, uh, ul, bM[buf], bM[buf] + 1280, bM[buf] + 2560, bM[buf] + 3328,
                   aX, lane);
    twr(aX, T[w], lane);
    trd(T[w], lane, Xhi, Xlo);
    __syncthreads();
  }
  short8 Zhi, Zlo;
  {
    const float* zp = zin + ((size_t)ch * SROWS + row) * 32 + quad * 8;
#pragma unroll
    for (int j = 0; j < 8; ++j) {
      float v = zp[j];
      unsigned short h = bf16u(v);
      Zhi[j] = (short)h;
      Zlo[j] = (short)bf16u(v - bf2f(h));
    }
  }
  stA(s + CHS - 1, 0);
  up.fetch(U, nullptr, row, s + CHS - 1, qq);
  __syncthreads();
  f32x4 aZ[2];
#pragma unroll 2
  for (int t = 0; t < CHS; ++t) {
    const int k = s + CHS - 1 - t, buf = t & 1;
    if (t < CHS - 1) stA(k - 1, buf ^ 1);
    short8 uh, ul;
    up.get(uh, ul);
    if (t < CHS - 1) up.fetch(U, nullptr, row, k - 1, qq);
    const f32x4 z4 = {0.f, 0.f, 0.f, 0.f};
    const short8 gf = ldfrag32(bO[buf], lane, 0);
    f32x4 ya = MFMA16(Zhi, gf, z4);
    ya = MFMA16(Zlo, gf, ya);
    {
      const size_t obase = (size_t)(tile * 64 + w * 16 + quad * 4) * 8192 + (size_t)k * 16 + cidx;
      if constexpr (DT == 0) {
        short* o = (short*)out;
#pragma unroll
        for (int r = 0; r < 4; ++r) {
          const float c = bf2f((unsigned short)o[obase + (size_t)r * 8192]);
          o[obase + (size_t)r * 8192] = (short)bf16u(c + ya[r]);
        }
      } else {
        float* o = (float*)out;
#pragma unroll
        for (int r = 0; r < 4; ++r) o[obase + (size_t)r * 8192] += ya[r];
      }
    }
    step_state<DT>(Zhi, Zlo, uh, ul, bM[buf], bM[buf] + 1280, bM[buf] + 2560, bM[buf] + 3328,
                   aZ, lane);
    twr(aZ, T[w], lane);
    trd(T[w], lane, Zhi, Zlo);
    __syncthreads();
  }
}

extern "C" void kernel_launch(void* const* d_in, const int* in_sizes, int n_in,
                              void* d_out, int out_size, void* d_ws, size_t ws_size,
                              hipStream_t stream) {
  (void)in_sizes; (void)n_in; (void)out_size;
  const void* U = d_in[0];
  const void* A = d_in[1];
  const void* B = d_in[2];
  const void* C = d_in[3];
  const void* D = d_in[4];
  const void* E = d_in[5];
  const void* F = d_in[6];
  const void* G = d_in[7];
  const void* bias = d_in[8];

  constexpr size_t SC1 = (size_t)NCH * SROWS * 32;
  constexpr size_t PBL = (size_t)256 * 5120 * 2 * 2 + (size_t)256 * 2560 * 2 * 2;  // 7,864,320
  constexpr size_t UBB = (size_t)BATCH * 1024 * 32;                                 // 134,217,728
  constexpr size_t NEED1 = 1024 + PBL + SC1 * 8;
  constexpr size_t NEED2 = NEED1 + UBB;
  const int mode = (ws_size >= NEED2) ? 2 : (ws_size >= NEED1 ? 1 : 0);

  char* base = (char*)d_ws;
  int* flag = (int*)base;
  short* ABp = (short*)(base + 1024);
  short* EFp = ABp + (size_t)256 * 5120;
  short* Ycp = EFp + (size_t)256 * 5120;
  short* Yap = Ycp + (size_t)256 * 2560;
  float* Sc = (mode >= 1) ? (float*)(Yap + (size_t)256 * 2560) : (float*)(base + 1024);
  float* Sa = Sc + SC1;
  short* Ub = (short*)(Sa + SC1);

  k_detect<<<1, 64, 0, stream>>>((const unsigned short*)U, flag);
  if (mode >= 1) {
    k_prep_pair<0><<<256, 256, 0, stream>>>(flag, A, B, C, D, E, F, G, ABp, EFp, Ycp, Yap);
    k_prep_pair<1><<<256, 256, 0, stream>>>(flag, A, B, C, D, E, F, G, ABp, EFp, Ycp, Yap);
  }
  if (mode == 2) k_prepU<<<16384, 256, 0, stream>>>(flag, (const float*)U, Ub);

  if (mode >= 1) {
    k1_pair<0, 1><<<dim3(NCH, 33), 256, 0, stream>>>(flag, U, ABp, EFp, Ub, Sc, Sa);
    if (mode == 2)
      k1_pair<1, 2><<<dim3(NCH, 33), 256, 0, stream>>>(flag, U, ABp, EFp, Ub, Sc, Sa);
    else
      k1_pair<1, 1><<<dim3(NCH, 33), 256, 0, stream>>>(flag, U, ABp, EFp, Ub, Sc, Sa);
    k2_comb<<<dim3(BATCH / 8, 2), 256, 0, stream>>>(Sc, Sa);
    k3_pair<0, 1><<<dim3(NCH, 32), 256, 0, stream>>>(flag, U, bias, ABp, EFp, Ycp, Yap, Ub,
                                                     Sc, Sa, d_out);
    if (mode == 2)
      k3_pair<1, 2><<<dim3(NCH, 32), 256, 0, stream>>>(flag, U, bias, ABp, EFp, Ycp, Yap, Ub,
                                                       Sc, Sa, d_out);
    else
      k3_pair<1, 1><<<dim3(NCH, 32), 256, 0, stream>>>(flag, U, bias, ABp, EFp, Ycp, Yap, Ub,
                                                       Sc, Sa, d_out);
  } else {
    k1_scan0<0><<<dim3(NCH, 65), 256, 0, stream>>>(flag, U, A, B, E, F, Sc, Sa);
    k1_scan0<1><<<dim3(NCH, 65), 256, 0, stream>>>(flag, U, A, B, E, F, Sc, Sa);
    k2_comb<<<dim3(BATCH / 8, 2), 256, 0, stream>>>(Sc, Sa);
    k3_legacy<0><<<dim3(NCH, 64), 256, 0, stream>>>(flag, U, A, B, C, D, E, F, G, bias,
                                                    Sc, Sa, d_out);
    k3_legacy<1><<<dim3(NCH, 64), 256, 0, stream>>>(flag, U, A, B, C, D, E, F, G, bias,
                                                    Sc, Sa, d_out);
  }
}